// Round 2
// baseline (2277.860 us; speedup 1.0000x reference)
//
#include <hip/hip_runtime.h>
#include <hip/hip_bf16.h>
#include <cstdint>
#include <cstddef>

#define D 128

typedef __hip_bfloat16 bf16;

// ---------- typed load/store helpers (storage T, compute fp32) ----------
__device__ inline float ld1(const float* p) { return *p; }
__device__ inline float ld1(const bf16* p) { return __bfloat162float(*p); }
__device__ inline float2 ld2(const float* p) { return *(const float2*)p; }
__device__ inline float2 ld2(const bf16* p) {
  __hip_bfloat162 v = *(const __hip_bfloat162*)p;
  float2 r; r.x = __bfloat162float(v.x); r.y = __bfloat162float(v.y); return r;
}
__device__ inline void st2(float* p, float a, float b) {
  float2 v; v.x = a; v.y = b; *(float2*)p = v;
}
__device__ inline void st2(bf16* p, float a, float b) {
  __hip_bfloat162 v; v.x = __float2bfloat16(a); v.y = __float2bfloat16(b);
  *(__hip_bfloat162*)p = v;
}

// ---------- u[l,rel,side][k] = sum_j W[l,rel,k,j] * a[l,rel,j] ----------
__global__ void compute_u_kernel(const float* __restrict__ Wsrc, const float* __restrict__ Wdst,
                                 const float* __restrict__ asrc, const float* __restrict__ adst,
                                 float* __restrict__ u) {
  int lr = blockIdx.x;       // (l*3+rel)
  int side = blockIdx.y;     // 0=src, 1=dst
  int k = threadIdx.x;       // 0..127
  const float* W = (side == 0 ? Wsrc : Wdst) + ((size_t)lr * D + k) * D;
  const float* a = (side == 0 ? asrc : adst) + (size_t)lr * D;
  float s = 0.f;
  for (int j = 0; j < D; ++j) s += W[j] * a[j];
  u[((size_t)lr * 2 + side) * D + k] = s;
}

// ---------- CSR build ----------
__global__ void count_kernel(const int* __restrict__ dst, int* __restrict__ cnt, int E) {
  int i = blockIdx.x * blockDim.x + threadIdx.x;
  if (i < E) atomicAdd(&cnt[dst[i]], 1);
}

__global__ void scan_kernel(int* __restrict__ cnt, int* __restrict__ rowptr, int n) {
  __shared__ int sums[1024];
  int t = threadIdx.x;
  int chunk = (n + 1023) / 1024;
  int base = t * chunk;
  int end = base + chunk; if (end > n) end = n;
  int s = 0;
  for (int i = base; i < end; ++i) s += cnt[i];
  sums[t] = s;
  __syncthreads();
  for (int off = 1; off < 1024; off <<= 1) {
    int v = (t >= off) ? sums[t - off] : 0;
    __syncthreads();
    sums[t] += v;
    __syncthreads();
  }
  int run = (t == 0) ? 0 : sums[t - 1];
  for (int i = base; i < end; ++i) {
    int c = cnt[i];          // read BEFORE overwrite (cursor aliases counts)
    rowptr[i] = run;
    cnt[i] = run;
    run += c;
  }
  if (t == 1023) rowptr[n] = sums[1023];
}

__global__ void fill_kernel(const int* __restrict__ dst, const int* __restrict__ src,
                            int* __restrict__ cursor, int* __restrict__ col, int E) {
  int i = blockIdx.x * blockDim.x + threadIdx.x;
  if (i < E) {
    int p = atomicAdd(&cursor[dst[i]], 1);
    col[p] = src[i];
  }
}

// ---------- matvec bundles: one wave per row ----------
template<typename Tin>
__global__ void vec4_kernel(const Tin* __restrict__ x,
                            const float* __restrict__ u0, const float* __restrict__ u1,
                            const float* __restrict__ u2, const float* __restrict__ u3,
                            float* __restrict__ o0, float* __restrict__ o1,
                            float* __restrict__ o2, float* __restrict__ o3, int n) {
  int gw = (int)(((size_t)blockIdx.x * blockDim.x + threadIdx.x) >> 6);
  int lane = threadIdx.x & 63;
  if (gw >= n) return;
  const Tin* xr = x + (size_t)gw * D;
  float xa = ld1(&xr[lane]), xb = ld1(&xr[lane + 64]);
  float p0 = xa * u0[lane] + xb * u0[lane + 64];
  float p1 = xa * u1[lane] + xb * u1[lane + 64];
  float p2 = xa * u2[lane] + xb * u2[lane + 64];
  float p3 = xa * u3[lane] + xb * u3[lane + 64];
  #pragma unroll
  for (int off = 32; off; off >>= 1) {
    p0 += __shfl_xor(p0, off);
    p1 += __shfl_xor(p1, off);
    p2 += __shfl_xor(p2, off);
    p3 += __shfl_xor(p3, off);
  }
  if (lane == 0) { o0[gw] = p0; o1[gw] = p1; o2[gw] = p2; o3[gw] = p3; }
}

template<typename Tin>
__global__ void vec2_kernel(const Tin* __restrict__ x,
                            const float* __restrict__ u0, const float* __restrict__ u1,
                            float* __restrict__ o0, float* __restrict__ o1, int n) {
  int gw = (int)(((size_t)blockIdx.x * blockDim.x + threadIdx.x) >> 6);
  int lane = threadIdx.x & 63;
  if (gw >= n) return;
  const Tin* xr = x + (size_t)gw * D;
  float xa = ld1(&xr[lane]), xb = ld1(&xr[lane + 64]);
  float p0 = xa * u0[lane] + xb * u0[lane + 64];
  float p1 = xa * u1[lane] + xb * u1[lane + 64];
  #pragma unroll
  for (int off = 32; off; off >>= 1) {
    p0 += __shfl_xor(p0, off);
    p1 += __shfl_xor(p1, off);
  }
  if (lane == 0) { o0[gw] = p0; o1[gw] = p1; }
}

// ---------- H = X @ W  ([N,128]@[128,128]); 32 rows/block, 32 KB LDS ----------
template<typename Tin, typename Tout>
__global__ __launch_bounds__(256) void matmul_kernel(const Tin* __restrict__ X,
                                                     const float* __restrict__ W,
                                                     Tout* __restrict__ H) {
  __shared__ float Wl[32 * D];   // 16 KB: 32 k-rows of W
  __shared__ float Xl[32 * D];   // 16 KB: 32 x-rows
  int tid = threadIdx.x;
  size_t row0 = (size_t)blockIdx.x * 32;
  const Tin* Xb = X + row0 * D;
  for (int i = 2 * tid; i < 32 * D; i += 512) {
    float2 v = ld2(&Xb[i]);
    Xl[i] = v.x; Xl[i + 1] = v.y;
  }
  int wv = tid >> 6, lane = tid & 63;
  float acc0[8], acc1[8];
  #pragma unroll
  for (int r = 0; r < 8; ++r) { acc0[r] = 0.f; acc1[r] = 0.f; }
  for (int kb = 0; kb < D; kb += 32) {
    __syncthreads();   // waves done with previous Wl chunk (and X staged, 1st iter)
    const float4* W4 = (const float4*)(W + (size_t)kb * D);
    float4* Wl4 = (float4*)Wl;
    #pragma unroll
    for (int i = 0; i < 4; ++i) Wl4[tid + 256 * i] = W4[tid + 256 * i];
    __syncthreads();
    const float* xbase = &Xl[(wv * 8) * D + kb];
    #pragma unroll
    for (int k = 0; k < 32; k += 4) {
      float2 w0 = *(const float2*)&Wl[(k + 0) * D + 2 * lane];
      float2 w1 = *(const float2*)&Wl[(k + 1) * D + 2 * lane];
      float2 w2 = *(const float2*)&Wl[(k + 2) * D + 2 * lane];
      float2 w3 = *(const float2*)&Wl[(k + 3) * D + 2 * lane];
      #pragma unroll
      for (int r = 0; r < 8; ++r) {
        float4 xv4 = *(const float4*)&xbase[r * D + k];
        acc0[r] += xv4.x * w0.x + xv4.y * w1.x + xv4.z * w2.x + xv4.w * w3.x;
        acc1[r] += xv4.x * w0.y + xv4.y * w1.y + xv4.z * w2.y + xv4.w * w3.y;
      }
    }
  }
  Tout* Hb = H + row0 * D;
  #pragma unroll
  for (int r = 0; r < 8; ++r) st2(&Hb[(size_t)(wv * 8 + r) * D + 2 * lane], acc0[r], acc1[r]);
}

// ---------- GAT aggregation: one wave per destination node ----------
// mode 0: out = agg + b                 mode 1: out = relu(out + agg + b)
// mode 2: out = relu(agg + b)
template<typename T>
__global__ void agg_kernel(const int* __restrict__ rowptr, const int* __restrict__ col,
                           const float* __restrict__ es, const float* __restrict__ ed,
                           const T* __restrict__ hs, const float* __restrict__ bias,
                           T* __restrict__ out, int ndst, int mode) {
  int gw = (int)(((size_t)blockIdx.x * blockDim.x + threadIdx.x) >> 6);
  int lane = threadIdx.x & 63;
  if (gw >= ndst) return;
  int p0 = rowptr[gw];
  int deg = rowptr[gw + 1] - p0;
  float a0 = 0.f, a1 = 0.f;
  if (deg > 0) {
    float edst = ed[gw];
    if (deg <= 64) {
      int s = 0; float e = -3.0e38f;
      if (lane < deg) {
        s = col[p0 + lane];
        float t = es[s] + edst;
        e = t > 0.f ? t : 0.2f * t;
      }
      float m = e;
      #pragma unroll
      for (int off = 32; off; off >>= 1) m = fmaxf(m, __shfl_xor(m, off));
      float ex = (lane < deg) ? __expf(e - m) : 0.f;
      float den = ex;
      #pragma unroll
      for (int off = 32; off; off >>= 1) den += __shfl_xor(den, off);
      float al = ex / (den + 1e-16f);
      for (int q = 0; q < deg; ++q) {
        float alpha = __shfl(al, q);
        int sq = __shfl(s, q);
        float2 h = ld2(&hs[(size_t)sq * D + 2 * lane]);
        a0 += alpha * h.x;
        a1 += alpha * h.y;
      }
    } else {
      float m = -3.0e38f;
      for (int j = lane; j < deg; j += 64) {
        int s = col[p0 + j];
        float t = es[s] + edst;
        t = t > 0.f ? t : 0.2f * t;
        m = fmaxf(m, t);
      }
      #pragma unroll
      for (int off = 32; off; off >>= 1) m = fmaxf(m, __shfl_xor(m, off));
      float den = 0.f;
      for (int j = lane; j < deg; j += 64) {
        int s = col[p0 + j];
        float t = es[s] + edst;
        t = t > 0.f ? t : 0.2f * t;
        den += __expf(t - m);
      }
      #pragma unroll
      for (int off = 32; off; off >>= 1) den += __shfl_xor(den, off);
      float inv = 1.f / (den + 1e-16f);
      for (int c = 0; c < deg; c += 64) {
        int j = c + lane;
        int s = 0; float al = 0.f;
        if (j < deg) {
          s = col[p0 + j];
          float t = es[s] + edst;
          t = t > 0.f ? t : 0.2f * t;
          al = __expf(t - m) * inv;
        }
        int cnt = deg - c; if (cnt > 64) cnt = 64;
        for (int q = 0; q < cnt; ++q) {
          float alpha = __shfl(al, q);
          int sq = __shfl(s, q);
          float2 h = ld2(&hs[(size_t)sq * D + 2 * lane]);
          a0 += alpha * h.x;
          a1 += alpha * h.y;
        }
      }
    }
  }
  float b0 = bias[2 * lane], b1 = bias[2 * lane + 1];
  size_t o = (size_t)gw * D + 2 * lane;
  if (mode == 0) {
    st2(&out[o], a0 + b0, a1 + b1);
  } else if (mode == 1) {
    float2 cur = ld2(&out[o]);
    float v0 = cur.x + a0 + b0, v1 = cur.y + a1 + b1;
    st2(&out[o], v0 > 0.f ? v0 : 0.f, v1 > 0.f ? v1 : 0.f);
  } else {
    float v0 = a0 + b0, v1 = a1 + b1;
    st2(&out[o], v0 > 0.f ? v0 : 0.f, v1 > 0.f ? v1 : 0.f);
  }
}

// ---------- pooling over sorted batch ids ----------
template<typename T>
__global__ void pool_kernel(const T* __restrict__ xv, const int* __restrict__ batch,
                            float* __restrict__ pooled, float* __restrict__ cntf, int rowsPerBlock) {
  int j = threadIdx.x;      // 0..127
  int r0 = blockIdx.x * rowsPerBlock;
  int cur = batch[r0];
  float s = 0.f;
  int run = 0;
  for (int r = r0; r < r0 + rowsPerBlock; ++r) {
    int b = batch[r];
    if (b != cur) {
      atomicAdd(&pooled[(size_t)cur * D + j], s);
      if (j == 0) atomicAdd(&cntf[cur], (float)run);
      s = 0.f; run = 0; cur = b;
    }
    s += ld1(&xv[(size_t)r * D + j]);
    run++;
  }
  atomicAdd(&pooled[(size_t)cur * D + j], s);
  if (j == 0) atomicAdd(&cntf[cur], (float)run);
}

// ---------- final MLP (single block) ----------
__global__ void mlp_kernel(const float* __restrict__ pooled, const float* __restrict__ cntf,
                           const float* __restrict__ w1, const float* __restrict__ b1,
                           const float* __restrict__ w2, const float* __restrict__ b2,
                           float* __restrict__ out, int B) {
  __shared__ float P[32 * D];
  __shared__ float Hs[32 * D];
  int tid = threadIdx.x;
  if (B > 32) return;
  for (int i = tid; i < B * D; i += 256) {
    int r = i >> 7;
    P[i] = pooled[i] / fmaxf(cntf[r], 1.0f);
  }
  __syncthreads();
  for (int i = tid; i < B * D; i += 256) {
    int r = i >> 7, j = i & 127;
    float s = b1[j];
    for (int k = 0; k < D; ++k) s += P[r * D + k] * w1[k * D + j];
    Hs[i] = s > 0.f ? s : 0.f;
  }
  __syncthreads();
  if (tid < B) {
    float s = b2[0];
    for (int j = 0; j < D; ++j) s += Hs[tid * D + j] * w2[j];
    out[tid] = s;
  }
}

__global__ void zero_kernel(float* __restrict__ o, int n) {
  int i = blockIdx.x * blockDim.x + threadIdx.x;
  if (i < n) o[i] = 0.f;
}

// ---------- full pipeline, templated on storage type ----------
template<typename T>
static void run_all(const float* x_var, const float* x_con,
                    const float* W_src, const float* W_dst,
                    const float* att_src, const float* att_dst, const float* bias,
                    const float* mlp_w1, const float* mlp_b1,
                    const float* mlp_w2, const float* mlp_b2,
                    const int* e_neg_src, const int* e_neg_dst,
                    const int* e_con_src, const int* e_con_dst, const int* batch_var,
                    int V, int C, int L, int EN, int EC, int B,
                    char* ws, float* out, hipStream_t stream) {
  size_t off = 0;
  auto alloc = [&](size_t bytes) -> char* {
    char* p = ws + off;
    off = (off + bytes + 255) & ~(size_t)255;
    return p;
  };
  T* xv0 = (T*)alloc((size_t)V * D * sizeof(T));
  T* xv1 = (T*)alloc((size_t)V * D * sizeof(T));
  T* xc  = (T*)alloc((size_t)C * D * sizeof(T));
  T* hs  = (T*)alloc((size_t)V * D * sizeof(T));   // shared across the 3 relations
  float* es0 = (float*)alloc((size_t)V * 4);
  float* ed0 = (float*)alloc((size_t)V * 4);
  float* es1 = (float*)alloc((size_t)V * 4);
  float* ed2 = (float*)alloc((size_t)V * 4);
  float* es2 = (float*)alloc((size_t)C * 4);
  float* ed1 = (float*)alloc((size_t)C * 4);
  float* u   = (float*)alloc((size_t)L * 3 * 2 * D * 4);
  int* rp0  = (int*)alloc((size_t)(V + 1) * 4);
  int* cur0 = (int*)alloc((size_t)V * 4);
  int* col0 = (int*)alloc((size_t)EN * 4);
  int* rp1  = (int*)alloc((size_t)(C + 1) * 4);
  int* cur1 = (int*)alloc((size_t)C * 4);
  int* col1 = (int*)alloc((size_t)EC * 4);
  int* rp2  = (int*)alloc((size_t)(V + 1) * 4);
  int* cur2 = (int*)alloc((size_t)V * 4);
  int* col2 = (int*)alloc((size_t)EC * 4);
  float* pooled = (float*)alloc((size_t)B * D * 4);
  float* cntf   = (float*)alloc((size_t)B * 4);

  hipMemsetAsync(cur0, 0, (size_t)V * 4, stream);
  hipMemsetAsync(cur1, 0, (size_t)C * 4, stream);
  hipMemsetAsync(cur2, 0, (size_t)V * 4, stream);
  hipMemsetAsync(pooled, 0, (size_t)B * D * 4, stream);
  hipMemsetAsync(cntf, 0, (size_t)B * 4, stream);

  compute_u_kernel<<<dim3(L * 3, 2), D, 0, stream>>>(W_src, W_dst, att_src, att_dst, u);

  const int tb = 256;
  count_kernel<<<(EN + tb - 1) / tb, tb, 0, stream>>>(e_neg_dst, cur0, EN);
  count_kernel<<<(EC + tb - 1) / tb, tb, 0, stream>>>(e_con_dst, cur1, EC);
  count_kernel<<<(EC + tb - 1) / tb, tb, 0, stream>>>(e_con_src, cur2, EC);
  scan_kernel<<<1, 1024, 0, stream>>>(cur0, rp0, V);
  scan_kernel<<<1, 1024, 0, stream>>>(cur1, rp1, C);
  scan_kernel<<<1, 1024, 0, stream>>>(cur2, rp2, V);
  fill_kernel<<<(EN + tb - 1) / tb, tb, 0, stream>>>(e_neg_dst, e_neg_src, cur0, col0, EN);
  fill_kernel<<<(EC + tb - 1) / tb, tb, 0, stream>>>(e_con_dst, e_con_src, cur1, col1, EC);
  fill_kernel<<<(EC + tb - 1) / tb, tb, 0, stream>>>(e_con_src, e_con_dst, cur2, col2, EC);

  auto U  = [&](int l, int rel, int side) { return u + (((size_t)l * 3 + rel) * 2 + side) * D; };
  auto Wp = [&](int l, int rel) { return W_src + ((size_t)l * 3 + rel) * D * D; };
  auto Bp = [&](int l, int rel) { return bias + ((size_t)l * 3 + rel) * D; };

  T* xv_final = xv0;
  for (int l = 0; l < L; ++l) {
    if (l == 0) {
      vec4_kernel<float><<<(V + 3) / 4, 256, 0, stream>>>(
          x_var, U(l,0,0), U(l,0,1), U(l,1,0), U(l,2,1), es0, ed0, es1, ed2, V);
      vec2_kernel<float><<<(C + 3) / 4, 256, 0, stream>>>(
          x_con, U(l,2,0), U(l,1,1), es2, ed1, C);
      matmul_kernel<float, T><<<V / 32, 256, 0, stream>>>(x_var, Wp(l,0), hs);
      agg_kernel<T><<<(V + 3) / 4, 256, 0, stream>>>(rp0, col0, es0, ed0, hs, Bp(l,0), xv0, V, 0);
      matmul_kernel<float, T><<<C / 32, 256, 0, stream>>>(x_con, Wp(l,2), hs);
      agg_kernel<T><<<(V + 3) / 4, 256, 0, stream>>>(rp2, col2, es2, ed2, hs, Bp(l,2), xv0, V, 1);
      matmul_kernel<float, T><<<V / 32, 256, 0, stream>>>(x_var, Wp(l,1), hs);
      agg_kernel<T><<<(C + 3) / 4, 256, 0, stream>>>(rp1, col1, es1, ed1, hs, Bp(l,1), xc, C, 2);
      xv_final = xv0;
    } else {
      T* xin  = (l & 1) ? xv0 : xv1;
      T* xout = (l & 1) ? xv1 : xv0;
      vec4_kernel<T><<<(V + 3) / 4, 256, 0, stream>>>(
          xin, U(l,0,0), U(l,0,1), U(l,1,0), U(l,2,1), es0, ed0, es1, ed2, V);
      vec2_kernel<T><<<(C + 3) / 4, 256, 0, stream>>>(
          xc, U(l,2,0), U(l,1,1), es2, ed1, C);
      matmul_kernel<T, T><<<V / 32, 256, 0, stream>>>(xin, Wp(l,0), hs);
      agg_kernel<T><<<(V + 3) / 4, 256, 0, stream>>>(rp0, col0, es0, ed0, hs, Bp(l,0), xout, V, 0);
      matmul_kernel<T, T><<<C / 32, 256, 0, stream>>>(xc, Wp(l,2), hs);
      agg_kernel<T><<<(V + 3) / 4, 256, 0, stream>>>(rp2, col2, es2, ed2, hs, Bp(l,2), xout, V, 1);
      matmul_kernel<T, T><<<V / 32, 256, 0, stream>>>(xin, Wp(l,1), hs);   // xin still intact
      agg_kernel<T><<<(C + 3) / 4, 256, 0, stream>>>(rp1, col1, es1, ed1, hs, Bp(l,1), xc, C, 2);
      xv_final = xout;
    }
  }

  pool_kernel<T><<<V / 128, 128, 0, stream>>>(xv_final, batch_var, pooled, cntf, 128);
  mlp_kernel<<<1, 256, 0, stream>>>(pooled, cntf, mlp_w1, mlp_b1, mlp_w2, mlp_b2, out, B);
}

extern "C" void kernel_launch(void* const* d_in, const int* in_sizes, int n_in,
                              void* d_out, int out_size, void* d_ws, size_t ws_size,
                              hipStream_t stream) {
  const float* x_var   = (const float*)d_in[0];
  const float* x_con   = (const float*)d_in[1];
  const float* W_src   = (const float*)d_in[2];
  const float* W_dst   = (const float*)d_in[3];
  const float* att_src = (const float*)d_in[4];
  const float* att_dst = (const float*)d_in[5];
  const float* bias    = (const float*)d_in[6];
  const float* mlp_w1  = (const float*)d_in[7];
  const float* mlp_b1  = (const float*)d_in[8];
  const float* mlp_w2  = (const float*)d_in[9];
  const float* mlp_b2  = (const float*)d_in[10];
  const int* e_neg_src = (const int*)d_in[11];
  const int* e_neg_dst = (const int*)d_in[12];
  const int* e_con_src = (const int*)d_in[13];
  const int* e_con_dst = (const int*)d_in[14];
  const int* batch_var = (const int*)d_in[15];
  (void)n_in;

  const int V  = in_sizes[0] / D;
  const int C  = in_sizes[1] / D;
  const int L  = in_sizes[2] / (3 * D * D);
  const int EN = in_sizes[11];
  const int EC = in_sizes[13];
  const int B  = out_size;

  // plan workspace for a given feature-storage element size
  auto plan = [&](size_t esz) -> size_t {
    size_t o = 0;
    auto add = [&](size_t b) { o = (o + b + 255) & ~(size_t)255; };
    add((size_t)V * D * esz); add((size_t)V * D * esz);
    add((size_t)C * D * esz); add((size_t)V * D * esz);
    add((size_t)V * 4); add((size_t)V * 4); add((size_t)V * 4); add((size_t)V * 4);
    add((size_t)C * 4); add((size_t)C * 4);
    add((size_t)L * 3 * 2 * D * 4);
    add((size_t)(V + 1) * 4); add((size_t)V * 4); add((size_t)EN * 4);
    add((size_t)(C + 1) * 4); add((size_t)C * 4); add((size_t)EC * 4);
    add((size_t)(V + 1) * 4); add((size_t)V * 4); add((size_t)EC * 4);
    add((size_t)B * D * 4); add((size_t)B * 4);
    return o;
  };

  if (plan(4) <= ws_size) {
    run_all<float>(x_var, x_con, W_src, W_dst, att_src, att_dst, bias,
                   mlp_w1, mlp_b1, mlp_w2, mlp_b2,
                   e_neg_src, e_neg_dst, e_con_src, e_con_dst, batch_var,
                   V, C, L, EN, EC, B, (char*)d_ws, (float*)d_out, stream);
  } else if (plan(2) <= ws_size) {
    run_all<bf16>(x_var, x_con, W_src, W_dst, att_src, att_dst, bias,
                  mlp_w1, mlp_b1, mlp_w2, mlp_b2,
                  e_neg_src, e_neg_dst, e_con_src, e_con_dst, batch_var,
                  V, C, L, EN, EC, B, (char*)d_ws, (float*)d_out, stream);
  } else {
    // workspace too small even for bf16 tier: fail gracefully (no GPU fault)
    zero_kernel<<<(out_size + 63) / 64, 64, 0, stream>>>((float*)d_out, out_size);
  }
}

// Round 3
// 1592.450 us; speedup vs baseline: 1.4304x; 1.4304x over previous
//
#include <hip/hip_runtime.h>
#include <hip/hip_bf16.h>
#include <cstdint>
#include <cstddef>

#define D 128

typedef __hip_bfloat16 bf16;

// ---------- typed load/store helpers (storage T, compute fp32) ----------
__device__ inline float ld1(const float* p) { return *p; }
__device__ inline float ld1(const bf16* p) { return __bfloat162float(*p); }
__device__ inline float2 ld2(const float* p) { return *(const float2*)p; }
__device__ inline float2 ld2(const bf16* p) {
  __hip_bfloat162 v = *(const __hip_bfloat162*)p;
  float2 r; r.x = __bfloat162float(v.x); r.y = __bfloat162float(v.y); return r;
}
__device__ inline void st2(float* p, float a, float b) {
  float2 v; v.x = a; v.y = b; *(float2*)p = v;
}
__device__ inline void st2(bf16* p, float a, float b) {
  __hip_bfloat162 v; v.x = __float2bfloat16(a); v.y = __float2bfloat16(b);
  *(__hip_bfloat162*)p = v;
}

// ---------- u[l,rel,side][k] = sum_j W[l,rel,k,j] * a[l,rel,j] ----------
__global__ void compute_u_kernel(const float* __restrict__ Wsrc, const float* __restrict__ Wdst,
                                 const float* __restrict__ asrc, const float* __restrict__ adst,
                                 float* __restrict__ u) {
  int lr = blockIdx.x;       // (l*3+rel)
  int side = blockIdx.y;     // 0=src, 1=dst
  int k = threadIdx.x;       // 0..127
  const float* W = (side == 0 ? Wsrc : Wdst) + ((size_t)lr * D + k) * D;
  const float* a = (side == 0 ? asrc : adst) + (size_t)lr * D;
  float s = 0.f;
  for (int j = 0; j < D; ++j) s += W[j] * a[j];
  u[((size_t)lr * 2 + side) * D + k] = s;
}

// ---------- CSR build ----------
__global__ void count_kernel(const int* __restrict__ dst, int* __restrict__ cnt, int E) {
  int i = blockIdx.x * blockDim.x + threadIdx.x;
  if (i < E) atomicAdd(&cnt[dst[i]], 1);
}

// counts for both EC relations in one pass over the edge arrays
__global__ void count2_kernel(const int* __restrict__ csrc, const int* __restrict__ cdst,
                              int* __restrict__ cnt_bycon, int* __restrict__ cnt_byvar, int E) {
  int i = blockIdx.x * blockDim.x + threadIdx.x;
  if (i < E) {
    atomicAdd(&cnt_bycon[cdst[i]], 1);
    atomicAdd(&cnt_byvar[csrc[i]], 1);
  }
}

// pass 1: per-block sums of cnt chunks
__global__ void bsum_kernel(const int* __restrict__ cnt, int* __restrict__ bsums,
                            int n, int per_block) {
  __shared__ int red[256];
  int b = blockIdx.x, t = threadIdx.x;
  int base = b * per_block;
  int end = base + per_block; if (end > n) end = n;
  int s = 0;
  for (int i = base + t; i < end; i += 256) s += cnt[i];
  red[t] = s;
  __syncthreads();
  #pragma unroll
  for (int off = 128; off; off >>= 1) {
    if (t < off) red[t] += red[t + off];
    __syncthreads();
  }
  if (t == 0) bsums[b] = red[0];
}

// pass 2: single small block scans bsums (nb <= 1024) in-place to EXCLUSIVE; writes total
__global__ void bscan_kernel(int* __restrict__ bsums, int nb, int* __restrict__ total_out) {
  __shared__ int sh[1024];
  int t = threadIdx.x;
  int v = (t < nb) ? bsums[t] : 0;
  sh[t] = v;
  __syncthreads();
  for (int off = 1; off < 1024; off <<= 1) {
    int u = (t >= off) ? sh[t - off] : 0;
    __syncthreads();
    sh[t] += u;
    __syncthreads();
  }
  if (t < nb) bsums[t] = sh[t] - v;     // exclusive
  if (t == 1023) *total_out = sh[1023]; // rowptr[n] = E
}

// pass 3: per-block exclusive scan of chunk, add block offset, write rowptr+cursor
__global__ void scan_fill_kernel(const int* __restrict__ cnt, const int* __restrict__ bsums,
                                 int* __restrict__ rowptr, int* __restrict__ cursor,
                                 int n, int per_block) {
  __shared__ int sh[256];
  int b = blockIdx.x, t = threadIdx.x;
  int base = b * per_block;
  int end = base + per_block; if (end > n) end = n;
  int run = bsums[b];
  for (int tile = base; tile < end; tile += 256) {
    int i = tile + t;
    int c = (i < end) ? cnt[i] : 0;
    __syncthreads();          // previous iteration's sh reads complete
    sh[t] = c;
    __syncthreads();
    for (int off = 1; off < 256; off <<= 1) {
      int u = (t >= off) ? sh[t - off] : 0;
      __syncthreads();
      sh[t] += u;
      __syncthreads();
    }
    int excl = sh[t] - c;
    if (i < end) {
      rowptr[i] = run + excl;
      cursor[i] = run + excl;
    }
    run += sh[255];
  }
}

__global__ void fill_kernel(const int* __restrict__ dst, const int* __restrict__ src,
                            int* __restrict__ cursor, int* __restrict__ col, int E) {
  int i = blockIdx.x * blockDim.x + threadIdx.x;
  if (i < E) {
    int p = atomicAdd(&cursor[dst[i]], 1);
    col[p] = src[i];
  }
}

// both EC relations in one pass
__global__ void fill2_kernel(const int* __restrict__ csrc, const int* __restrict__ cdst,
                             int* __restrict__ cur_bycon, int* __restrict__ cur_byvar,
                             int* __restrict__ col_bycon, int* __restrict__ col_byvar, int E) {
  int i = blockIdx.x * blockDim.x + threadIdx.x;
  if (i < E) {
    int s = csrc[i], d = cdst[i];
    int p = atomicAdd(&cur_bycon[d], 1);
    col_bycon[p] = s;
    int q = atomicAdd(&cur_byvar[s], 1);
    col_byvar[q] = d;
  }
}

// ---------- matvec bundles: one wave per row ----------
template<typename Tin>
__global__ void vec4_kernel(const Tin* __restrict__ x,
                            const float* __restrict__ u0, const float* __restrict__ u1,
                            const float* __restrict__ u2, const float* __restrict__ u3,
                            float* __restrict__ o0, float* __restrict__ o1,
                            float* __restrict__ o2, float* __restrict__ o3, int n) {
  int gw = (int)(((size_t)blockIdx.x * blockDim.x + threadIdx.x) >> 6);
  int lane = threadIdx.x & 63;
  if (gw >= n) return;
  const Tin* xr = x + (size_t)gw * D;
  float xa = ld1(&xr[lane]), xb = ld1(&xr[lane + 64]);
  float p0 = xa * u0[lane] + xb * u0[lane + 64];
  float p1 = xa * u1[lane] + xb * u1[lane + 64];
  float p2 = xa * u2[lane] + xb * u2[lane + 64];
  float p3 = xa * u3[lane] + xb * u3[lane + 64];
  #pragma unroll
  for (int off = 32; off; off >>= 1) {
    p0 += __shfl_xor(p0, off);
    p1 += __shfl_xor(p1, off);
    p2 += __shfl_xor(p2, off);
    p3 += __shfl_xor(p3, off);
  }
  if (lane == 0) { o0[gw] = p0; o1[gw] = p1; o2[gw] = p2; o3[gw] = p3; }
}

template<typename Tin>
__global__ void vec2_kernel(const Tin* __restrict__ x,
                            const float* __restrict__ u0, const float* __restrict__ u1,
                            float* __restrict__ o0, float* __restrict__ o1, int n) {
  int gw = (int)(((size_t)blockIdx.x * blockDim.x + threadIdx.x) >> 6);
  int lane = threadIdx.x & 63;
  if (gw >= n) return;
  const Tin* xr = x + (size_t)gw * D;
  float xa = ld1(&xr[lane]), xb = ld1(&xr[lane + 64]);
  float p0 = xa * u0[lane] + xb * u0[lane + 64];
  float p1 = xa * u1[lane] + xb * u1[lane + 64];
  #pragma unroll
  for (int off = 32; off; off >>= 1) {
    p0 += __shfl_xor(p0, off);
    p1 += __shfl_xor(p1, off);
  }
  if (lane == 0) { o0[gw] = p0; o1[gw] = p1; }
}

// ---------- H = X @ W  ([N,128]@[128,128]); 32 rows/block, 32 KB LDS ----------
template<typename Tin, typename Tout>
__global__ __launch_bounds__(256) void matmul_kernel(const Tin* __restrict__ X,
                                                     const float* __restrict__ W,
                                                     Tout* __restrict__ H) {
  __shared__ float Wl[32 * D];   // 16 KB: 32 k-rows of W
  __shared__ float Xl[32 * D];   // 16 KB: 32 x-rows
  int tid = threadIdx.x;
  size_t row0 = (size_t)blockIdx.x * 32;
  const Tin* Xb = X + row0 * D;
  for (int i = 2 * tid; i < 32 * D; i += 512) {
    float2 v = ld2(&Xb[i]);
    Xl[i] = v.x; Xl[i + 1] = v.y;
  }
  int wv = tid >> 6, lane = tid & 63;
  float acc0[8], acc1[8];
  #pragma unroll
  for (int r = 0; r < 8; ++r) { acc0[r] = 0.f; acc1[r] = 0.f; }
  for (int kb = 0; kb < D; kb += 32) {
    __syncthreads();   // waves done with previous Wl chunk (and X staged, 1st iter)
    const float4* W4 = (const float4*)(W + (size_t)kb * D);
    float4* Wl4 = (float4*)Wl;
    #pragma unroll
    for (int i = 0; i < 4; ++i) Wl4[tid + 256 * i] = W4[tid + 256 * i];
    __syncthreads();
    const float* xbase = &Xl[(wv * 8) * D + kb];
    #pragma unroll
    for (int k = 0; k < 32; k += 4) {
      float2 w0 = *(const float2*)&Wl[(k + 0) * D + 2 * lane];
      float2 w1 = *(const float2*)&Wl[(k + 1) * D + 2 * lane];
      float2 w2 = *(const float2*)&Wl[(k + 2) * D + 2 * lane];
      float2 w3 = *(const float2*)&Wl[(k + 3) * D + 2 * lane];
      #pragma unroll
      for (int r = 0; r < 8; ++r) {
        float4 xv4 = *(const float4*)&xbase[r * D + k];
        acc0[r] += xv4.x * w0.x + xv4.y * w1.x + xv4.z * w2.x + xv4.w * w3.x;
        acc1[r] += xv4.x * w0.y + xv4.y * w1.y + xv4.z * w2.y + xv4.w * w3.y;
      }
    }
  }
  Tout* Hb = H + row0 * D;
  #pragma unroll
  for (int r = 0; r < 8; ++r) st2(&Hb[(size_t)(wv * 8 + r) * D + 2 * lane], acc0[r], acc1[r]);
}

// ---------- GAT aggregation: one wave per destination node ----------
// mode 0: out = agg + b                 mode 1: out = relu(out + agg + b)
// mode 2: out = relu(agg + b)
template<typename T>
__global__ void agg_kernel(const int* __restrict__ rowptr, const int* __restrict__ col,
                           const float* __restrict__ es, const float* __restrict__ ed,
                           const T* __restrict__ hs, const float* __restrict__ bias,
                           T* __restrict__ out, int ndst, int mode) {
  int gw = (int)(((size_t)blockIdx.x * blockDim.x + threadIdx.x) >> 6);
  int lane = threadIdx.x & 63;
  if (gw >= ndst) return;
  int p0 = rowptr[gw];
  int deg = rowptr[gw + 1] - p0;
  float a0 = 0.f, a1 = 0.f;
  if (deg > 0) {
    float edst = ed[gw];
    if (deg <= 64) {
      int s = 0; float e = -3.0e38f;
      if (lane < deg) {
        s = col[p0 + lane];
        float t = es[s] + edst;
        e = t > 0.f ? t : 0.2f * t;
      }
      float m = e;
      #pragma unroll
      for (int off = 32; off; off >>= 1) m = fmaxf(m, __shfl_xor(m, off));
      float ex = (lane < deg) ? __expf(e - m) : 0.f;
      float den = ex;
      #pragma unroll
      for (int off = 32; off; off >>= 1) den += __shfl_xor(den, off);
      float al = ex / (den + 1e-16f);
      for (int q = 0; q < deg; ++q) {
        float alpha = __shfl(al, q);
        int sq = __shfl(s, q);
        float2 h = ld2(&hs[(size_t)sq * D + 2 * lane]);
        a0 += alpha * h.x;
        a1 += alpha * h.y;
      }
    } else {
      float m = -3.0e38f;
      for (int j = lane; j < deg; j += 64) {
        int s = col[p0 + j];
        float t = es[s] + edst;
        t = t > 0.f ? t : 0.2f * t;
        m = fmaxf(m, t);
      }
      #pragma unroll
      for (int off = 32; off; off >>= 1) m = fmaxf(m, __shfl_xor(m, off));
      float den = 0.f;
      for (int j = lane; j < deg; j += 64) {
        int s = col[p0 + j];
        float t = es[s] + edst;
        t = t > 0.f ? t : 0.2f * t;
        den += __expf(t - m);
      }
      #pragma unroll
      for (int off = 32; off; off >>= 1) den += __shfl_xor(den, off);
      float inv = 1.f / (den + 1e-16f);
      for (int c = 0; c < deg; c += 64) {
        int j = c + lane;
        int s = 0; float al = 0.f;
        if (j < deg) {
          s = col[p0 + j];
          float t = es[s] + edst;
          t = t > 0.f ? t : 0.2f * t;
          al = __expf(t - m) * inv;
        }
        int cnt = deg - c; if (cnt > 64) cnt = 64;
        for (int q = 0; q < cnt; ++q) {
          float alpha = __shfl(al, q);
          int sq = __shfl(s, q);
          float2 h = ld2(&hs[(size_t)sq * D + 2 * lane]);
          a0 += alpha * h.x;
          a1 += alpha * h.y;
        }
      }
    }
  }
  float b0 = bias[2 * lane], b1 = bias[2 * lane + 1];
  size_t o = (size_t)gw * D + 2 * lane;
  if (mode == 0) {
    st2(&out[o], a0 + b0, a1 + b1);
  } else if (mode == 1) {
    float2 cur = ld2(&out[o]);
    float v0 = cur.x + a0 + b0, v1 = cur.y + a1 + b1;
    st2(&out[o], v0 > 0.f ? v0 : 0.f, v1 > 0.f ? v1 : 0.f);
  } else {
    float v0 = a0 + b0, v1 = a1 + b1;
    st2(&out[o], v0 > 0.f ? v0 : 0.f, v1 > 0.f ? v1 : 0.f);
  }
}

// ---------- pooling over sorted batch ids ----------
template<typename T>
__global__ void pool_kernel(const T* __restrict__ xv, const int* __restrict__ batch,
                            float* __restrict__ pooled, float* __restrict__ cntf, int rowsPerBlock) {
  int j = threadIdx.x;      // 0..127
  int r0 = blockIdx.x * rowsPerBlock;
  int cur = batch[r0];
  float s = 0.f;
  int run = 0;
  for (int r = r0; r < r0 + rowsPerBlock; ++r) {
    int b = batch[r];
    if (b != cur) {
      atomicAdd(&pooled[(size_t)cur * D + j], s);
      if (j == 0) atomicAdd(&cntf[cur], (float)run);
      s = 0.f; run = 0; cur = b;
    }
    s += ld1(&xv[(size_t)r * D + j]);
    run++;
  }
  atomicAdd(&pooled[(size_t)cur * D + j], s);
  if (j == 0) atomicAdd(&cntf[cur], (float)run);
}

// ---------- final MLP (single block) ----------
__global__ void mlp_kernel(const float* __restrict__ pooled, const float* __restrict__ cntf,
                           const float* __restrict__ w1, const float* __restrict__ b1,
                           const float* __restrict__ w2, const float* __restrict__ b2,
                           float* __restrict__ out, int B) {
  __shared__ float P[32 * D];
  __shared__ float Hs[32 * D];
  int tid = threadIdx.x;
  if (B > 32) return;
  for (int i = tid; i < B * D; i += 256) {
    int r = i >> 7;
    P[i] = pooled[i] / fmaxf(cntf[r], 1.0f);
  }
  __syncthreads();
  for (int i = tid; i < B * D; i += 256) {
    int r = i >> 7, j = i & 127;
    float s = b1[j];
    for (int k = 0; k < D; ++k) s += P[r * D + k] * w1[k * D + j];
    Hs[i] = s > 0.f ? s : 0.f;
  }
  __syncthreads();
  if (tid < B) {
    float s = b2[0];
    for (int j = 0; j < D; ++j) s += Hs[tid * D + j] * w2[j];
    out[tid] = s;
  }
}

__global__ void zero_kernel(float* __restrict__ o, int n) {
  int i = blockIdx.x * blockDim.x + threadIdx.x;
  if (i < n) o[i] = 0.f;
}

// ---------- full pipeline, templated on storage type ----------
template<typename T>
static void run_all(const float* x_var, const float* x_con,
                    const float* W_src, const float* W_dst,
                    const float* att_src, const float* att_dst, const float* bias,
                    const float* mlp_w1, const float* mlp_b1,
                    const float* mlp_w2, const float* mlp_b2,
                    const int* e_neg_src, const int* e_neg_dst,
                    const int* e_con_src, const int* e_con_dst, const int* batch_var,
                    int V, int C, int L, int EN, int EC, int B,
                    char* ws, float* out, hipStream_t stream) {
  size_t off = 0;
  auto alloc = [&](size_t bytes) -> char* {
    char* p = ws + off;
    off = (off + bytes + 255) & ~(size_t)255;
    return p;
  };
  T* xv0 = (T*)alloc((size_t)V * D * sizeof(T));
  T* xv1 = (T*)alloc((size_t)V * D * sizeof(T));
  T* xc  = (T*)alloc((size_t)C * D * sizeof(T));
  T* hs  = (T*)alloc((size_t)V * D * sizeof(T));   // shared across the 3 relations
  float* es0 = (float*)alloc((size_t)V * 4);
  float* ed0 = (float*)alloc((size_t)V * 4);
  float* es1 = (float*)alloc((size_t)V * 4);
  float* ed2 = (float*)alloc((size_t)V * 4);
  float* es2 = (float*)alloc((size_t)C * 4);
  float* ed1 = (float*)alloc((size_t)C * 4);
  float* u   = (float*)alloc((size_t)L * 3 * 2 * D * 4);
  int* rp0  = (int*)alloc((size_t)(V + 1) * 4);
  int* cur0 = (int*)alloc((size_t)V * 4);
  int* col0 = (int*)alloc((size_t)EN * 4);
  int* rp1  = (int*)alloc((size_t)(C + 1) * 4);
  int* cur1 = (int*)alloc((size_t)C * 4);
  int* col1 = (int*)alloc((size_t)EC * 4);
  int* rp2  = (int*)alloc((size_t)(V + 1) * 4);
  int* cur2 = (int*)alloc((size_t)V * 4);
  int* col2 = (int*)alloc((size_t)EC * 4);
  int* bsums = (int*)alloc((size_t)1024 * 4);
  float* pooled = (float*)alloc((size_t)B * D * 4);
  float* cntf   = (float*)alloc((size_t)B * 4);

  hipMemsetAsync(cur0, 0, (size_t)V * 4, stream);
  hipMemsetAsync(cur1, 0, (size_t)C * 4, stream);
  hipMemsetAsync(cur2, 0, (size_t)V * 4, stream);
  hipMemsetAsync(pooled, 0, (size_t)B * D * 4, stream);
  hipMemsetAsync(cntf, 0, (size_t)B * 4, stream);

  compute_u_kernel<<<dim3(L * 3, 2), D, 0, stream>>>(W_src, W_dst, att_src, att_dst, u);

  const int tb = 256;
  // counts (cur* serve as count buffers, then get rewritten as cursors by scan_fill)
  count_kernel<<<(EN + tb - 1) / tb, tb, 0, stream>>>(e_neg_dst, cur0, EN);
  count2_kernel<<<(EC + tb - 1) / tb, tb, 0, stream>>>(e_con_src, e_con_dst, cur1, cur2, EC);

  // parallel 3-pass scans
  auto scan = [&](int* cnt_and_cur, int* rowptr, int n) {
    int per_block = ((n + 1023) / 1024 + 255) & ~255;   // multiple of 256, nb<=1024
    if (per_block < 256) per_block = 256;
    int nb = (n + per_block - 1) / per_block;
    bsum_kernel<<<nb, 256, 0, stream>>>(cnt_and_cur, bsums, n, per_block);
    bscan_kernel<<<1, 1024, 0, stream>>>(bsums, nb, rowptr + n);
    scan_fill_kernel<<<nb, 256, 0, stream>>>(cnt_and_cur, bsums, rowptr, cnt_and_cur, n, per_block);
  };
  scan(cur0, rp0, V);
  scan(cur1, rp1, C);
  scan(cur2, rp2, V);

  fill_kernel<<<(EN + tb - 1) / tb, tb, 0, stream>>>(e_neg_dst, e_neg_src, cur0, col0, EN);
  fill2_kernel<<<(EC + tb - 1) / tb, tb, 0, stream>>>(e_con_src, e_con_dst, cur1, cur2, col1, col2, EC);

  auto U  = [&](int l, int rel, int side) { return u + (((size_t)l * 3 + rel) * 2 + side) * D; };
  auto Wp = [&](int l, int rel) { return W_src + ((size_t)l * 3 + rel) * D * D; };
  auto Bp = [&](int l, int rel) { return bias + ((size_t)l * 3 + rel) * D; };

  T* xv_final = xv0;
  for (int l = 0; l < L; ++l) {
    if (l == 0) {
      vec4_kernel<float><<<(V + 3) / 4, 256, 0, stream>>>(
          x_var, U(l,0,0), U(l,0,1), U(l,1,0), U(l,2,1), es0, ed0, es1, ed2, V);
      vec2_kernel<float><<<(C + 3) / 4, 256, 0, stream>>>(
          x_con, U(l,2,0), U(l,1,1), es2, ed1, C);
      matmul_kernel<float, T><<<V / 32, 256, 0, stream>>>(x_var, Wp(l,0), hs);
      agg_kernel<T><<<(V + 3) / 4, 256, 0, stream>>>(rp0, col0, es0, ed0, hs, Bp(l,0), xv0, V, 0);
      matmul_kernel<float, T><<<C / 32, 256, 0, stream>>>(x_con, Wp(l,2), hs);
      agg_kernel<T><<<(V + 3) / 4, 256, 0, stream>>>(rp2, col2, es2, ed2, hs, Bp(l,2), xv0, V, 1);
      matmul_kernel<float, T><<<V / 32, 256, 0, stream>>>(x_var, Wp(l,1), hs);
      agg_kernel<T><<<(C + 3) / 4, 256, 0, stream>>>(rp1, col1, es1, ed1, hs, Bp(l,1), xc, C, 2);
      xv_final = xv0;
    } else {
      T* xin  = (l & 1) ? xv0 : xv1;
      T* xout = (l & 1) ? xv1 : xv0;
      vec4_kernel<T><<<(V + 3) / 4, 256, 0, stream>>>(
          xin, U(l,0,0), U(l,0,1), U(l,1,0), U(l,2,1), es0, ed0, es1, ed2, V);
      vec2_kernel<T><<<(C + 3) / 4, 256, 0, stream>>>(
          xc, U(l,2,0), U(l,1,1), es2, ed1, C);
      matmul_kernel<T, T><<<V / 32, 256, 0, stream>>>(xin, Wp(l,0), hs);
      agg_kernel<T><<<(V + 3) / 4, 256, 0, stream>>>(rp0, col0, es0, ed0, hs, Bp(l,0), xout, V, 0);
      matmul_kernel<T, T><<<C / 32, 256, 0, stream>>>(xc, Wp(l,2), hs);
      agg_kernel<T><<<(V + 3) / 4, 256, 0, stream>>>(rp2, col2, es2, ed2, hs, Bp(l,2), xout, V, 1);
      matmul_kernel<T, T><<<V / 32, 256, 0, stream>>>(xin, Wp(l,1), hs);   // xin still intact
      agg_kernel<T><<<(C + 3) / 4, 256, 0, stream>>>(rp1, col1, es1, ed1, hs, Bp(l,1), xc, C, 2);
      xv_final = xout;
    }
  }

  pool_kernel<T><<<V / 128, 128, 0, stream>>>(xv_final, batch_var, pooled, cntf, 128);
  mlp_kernel<<<1, 256, 0, stream>>>(pooled, cntf, mlp_w1, mlp_b1, mlp_w2, mlp_b2, out, B);
}

extern "C" void kernel_launch(void* const* d_in, const int* in_sizes, int n_in,
                              void* d_out, int out_size, void* d_ws, size_t ws_size,
                              hipStream_t stream) {
  const float* x_var   = (const float*)d_in[0];
  const float* x_con   = (const float*)d_in[1];
  const float* W_src   = (const float*)d_in[2];
  const float* W_dst   = (const float*)d_in[3];
  const float* att_src = (const float*)d_in[4];
  const float* att_dst = (const float*)d_in[5];
  const float* bias    = (const float*)d_in[6];
  const float* mlp_w1  = (const float*)d_in[7];
  const float* mlp_b1  = (const float*)d_in[8];
  const float* mlp_w2  = (const float*)d_in[9];
  const float* mlp_b2  = (const float*)d_in[10];
  const int* e_neg_src = (const int*)d_in[11];
  const int* e_neg_dst = (const int*)d_in[12];
  const int* e_con_src = (const int*)d_in[13];
  const int* e_con_dst = (const int*)d_in[14];
  const int* batch_var = (const int*)d_in[15];
  (void)n_in;

  const int V  = in_sizes[0] / D;
  const int C  = in_sizes[1] / D;
  const int L  = in_sizes[2] / (3 * D * D);
  const int EN = in_sizes[11];
  const int EC = in_sizes[13];
  const int B  = out_size;

  // plan workspace for a given feature-storage element size
  auto plan = [&](size_t esz) -> size_t {
    size_t o = 0;
    auto add = [&](size_t b) { o = (o + b + 255) & ~(size_t)255; };
    add((size_t)V * D * esz); add((size_t)V * D * esz);
    add((size_t)C * D * esz); add((size_t)V * D * esz);
    add((size_t)V * 4); add((size_t)V * 4); add((size_t)V * 4); add((size_t)V * 4);
    add((size_t)C * 4); add((size_t)C * 4);
    add((size_t)L * 3 * 2 * D * 4);
    add((size_t)(V + 1) * 4); add((size_t)V * 4); add((size_t)EN * 4);
    add((size_t)(C + 1) * 4); add((size_t)C * 4); add((size_t)EC * 4);
    add((size_t)(V + 1) * 4); add((size_t)V * 4); add((size_t)EC * 4);
    add((size_t)1024 * 4);
    add((size_t)B * D * 4); add((size_t)B * 4);
    return o;
  };

  if (plan(4) <= ws_size) {
    run_all<float>(x_var, x_con, W_src, W_dst, att_src, att_dst, bias,
                   mlp_w1, mlp_b1, mlp_w2, mlp_b2,
                   e_neg_src, e_neg_dst, e_con_src, e_con_dst, batch_var,
                   V, C, L, EN, EC, B, (char*)d_ws, (float*)d_out, stream);
  } else if (plan(2) <= ws_size) {
    run_all<bf16>(x_var, x_con, W_src, W_dst, att_src, att_dst, bias,
                  mlp_w1, mlp_b1, mlp_w2, mlp_b2,
                  e_neg_src, e_neg_dst, e_con_src, e_con_dst, batch_var,
                  V, C, L, EN, EC, B, (char*)d_ws, (float*)d_out, stream);
  } else {
    // workspace too small even for bf16 tier: fail gracefully (no GPU fault)
    zero_kernel<<<(out_size + 63) / 64, 64, 0, stream>>>((float*)d_out, out_size);
  }
}

// Round 4
// 1507.794 us; speedup vs baseline: 1.5107x; 1.0561x over previous
//
#include <hip/hip_runtime.h>
#include <hip/hip_bf16.h>
#include <cstdint>
#include <cstddef>

#define D 128

typedef __hip_bfloat16 bf16;

typedef __attribute__((ext_vector_type(8))) short short8v;   // 8 bf16 (4 VGPR)
typedef __attribute__((ext_vector_type(4))) float f32x4;     // MFMA 16x16 acc

// ---------- typed load/store helpers (storage T, compute fp32) ----------
__device__ inline float ld1(const float* p) { return *p; }
__device__ inline float ld1(const bf16* p) { return __bfloat162float(*p); }
__device__ inline float2 ld2(const float* p) { return *(const float2*)p; }
__device__ inline float2 ld2(const bf16* p) {
  __hip_bfloat162 v = *(const __hip_bfloat162*)p;
  float2 r; r.x = __bfloat162float(v.x); r.y = __bfloat162float(v.y); return r;
}
__device__ inline void st2(float* p, float a, float b) {
  float2 v; v.x = a; v.y = b; *(float2*)p = v;
}
__device__ inline void st2(bf16* p, float a, float b) {
  __hip_bfloat162 v; v.x = __float2bfloat16(a); v.y = __float2bfloat16(b);
  *(__hip_bfloat162*)p = v;
}

// bf16 bit helpers (RNE)
__device__ inline short f2bf(float x) {
  uint32_t u = __builtin_bit_cast(uint32_t, x);
  uint32_t r = (u + 0x7FFFu + ((u >> 16) & 1u)) >> 16;
  return (short)(uint16_t)r;
}
__device__ inline float bf2f(short s) {
  uint32_t u = ((uint32_t)(uint16_t)s) << 16;
  return __builtin_bit_cast(float, u);
}

__device__ inline f32x4 mfma16(short8v a, short8v b, f32x4 c) {
  return __builtin_amdgcn_mfma_f32_16x16x32_bf16(a, b, c, 0, 0, 0);
}

// ---------- u[l,rel,side][k] = sum_j W[l,rel,k,j] * a[l,rel,j] ----------
__global__ void compute_u_kernel(const float* __restrict__ Wsrc, const float* __restrict__ Wdst,
                                 const float* __restrict__ asrc, const float* __restrict__ adst,
                                 float* __restrict__ u) {
  int lr = blockIdx.x;       // (l*3+rel)
  int side = blockIdx.y;     // 0=src, 1=dst
  int k = threadIdx.x;       // 0..127
  const float* W = (side == 0 ? Wsrc : Wdst) + ((size_t)lr * D + k) * D;
  const float* a = (side == 0 ? asrc : adst) + (size_t)lr * D;
  float s = 0.f;
  for (int j = 0; j < D; ++j) s += W[j] * a[j];
  u[((size_t)lr * 2 + side) * D + k] = s;
}

// ---------- W split: Wh/Wl bf16, transposed [col][k] for contiguous B-frags ----------
__global__ void wsplit_kernel(const float* __restrict__ Wsrc,
                              short* __restrict__ WhT, short* __restrict__ WlT) {
  int lr = blockIdx.x;
  const float* W = Wsrc + (size_t)lr * D * D;
  short* wh = WhT + (size_t)lr * D * D;
  short* wl = WlT + (size_t)lr * D * D;
  for (int i = threadIdx.x; i < D * D; i += blockDim.x) {
    int k = i >> 7, c = i & 127;
    float w = W[i];                       // W[k][c]
    short h = f2bf(w);
    short l = f2bf(w - bf2f(h));
    wh[c * D + k] = h;                    // transposed
    wl[c * D + k] = l;
  }
}

// ---------- CSR build ----------
__global__ void count_kernel(const int* __restrict__ dst, int* __restrict__ cnt, int E) {
  int i = blockIdx.x * blockDim.x + threadIdx.x;
  if (i < E) atomicAdd(&cnt[dst[i]], 1);
}

__global__ void count2_kernel(const int* __restrict__ csrc, const int* __restrict__ cdst,
                              int* __restrict__ cnt_bycon, int* __restrict__ cnt_byvar, int E) {
  int i = blockIdx.x * blockDim.x + threadIdx.x;
  if (i < E) {
    atomicAdd(&cnt_bycon[cdst[i]], 1);
    atomicAdd(&cnt_byvar[csrc[i]], 1);
  }
}

__global__ void bsum_kernel(const int* __restrict__ cnt, int* __restrict__ bsums,
                            int n, int per_block) {
  __shared__ int red[256];
  int b = blockIdx.x, t = threadIdx.x;
  int base = b * per_block;
  int end = base + per_block; if (end > n) end = n;
  int s = 0;
  for (int i = base + t; i < end; i += 256) s += cnt[i];
  red[t] = s;
  __syncthreads();
  #pragma unroll
  for (int off = 128; off; off >>= 1) {
    if (t < off) red[t] += red[t + off];
    __syncthreads();
  }
  if (t == 0) bsums[b] = red[0];
}

__global__ void bscan_kernel(int* __restrict__ bsums, int nb, int* __restrict__ total_out) {
  __shared__ int sh[1024];
  int t = threadIdx.x;
  int v = (t < nb) ? bsums[t] : 0;
  sh[t] = v;
  __syncthreads();
  for (int off = 1; off < 1024; off <<= 1) {
    int u = (t >= off) ? sh[t - off] : 0;
    __syncthreads();
    sh[t] += u;
    __syncthreads();
  }
  if (t < nb) bsums[t] = sh[t] - v;     // exclusive
  if (t == 1023) *total_out = sh[1023];
}

__global__ void scan_fill_kernel(const int* __restrict__ cnt, const int* __restrict__ bsums,
                                 int* __restrict__ rowptr, int* __restrict__ cursor,
                                 int n, int per_block) {
  __shared__ int sh[256];
  int b = blockIdx.x, t = threadIdx.x;
  int base = b * per_block;
  int end = base + per_block; if (end > n) end = n;
  int run = bsums[b];
  for (int tile = base; tile < end; tile += 256) {
    int i = tile + t;
    int c = (i < end) ? cnt[i] : 0;
    __syncthreads();
    sh[t] = c;
    __syncthreads();
    for (int off = 1; off < 256; off <<= 1) {
      int u = (t >= off) ? sh[t - off] : 0;
      __syncthreads();
      sh[t] += u;
      __syncthreads();
    }
    int excl = sh[t] - c;
    if (i < end) {
      rowptr[i] = run + excl;
      cursor[i] = run + excl;
    }
    run += sh[255];
  }
}

__global__ void fill_kernel(const int* __restrict__ dst, const int* __restrict__ src,
                            int* __restrict__ cursor, int* __restrict__ col, int E) {
  int i = blockIdx.x * blockDim.x + threadIdx.x;
  if (i < E) {
    int p = atomicAdd(&cursor[dst[i]], 1);
    col[p] = src[i];
  }
}

__global__ void fill2_kernel(const int* __restrict__ csrc, const int* __restrict__ cdst,
                             int* __restrict__ cur_bycon, int* __restrict__ cur_byvar,
                             int* __restrict__ col_bycon, int* __restrict__ col_byvar, int E) {
  int i = blockIdx.x * blockDim.x + threadIdx.x;
  if (i < E) {
    int s = csrc[i], d = cdst[i];
    int p = atomicAdd(&cur_bycon[d], 1);
    col_bycon[p] = s;
    int q = atomicAdd(&cur_byvar[s], 1);
    col_byvar[q] = d;
  }
}

// ---------- matvec bundles: one wave per row ----------
template<typename Tin>
__global__ void vec4_kernel(const Tin* __restrict__ x,
                            const float* __restrict__ u0, const float* __restrict__ u1,
                            const float* __restrict__ u2, const float* __restrict__ u3,
                            float* __restrict__ o0, float* __restrict__ o1,
                            float* __restrict__ o2, float* __restrict__ o3, int n) {
  int gw = (int)(((size_t)blockIdx.x * blockDim.x + threadIdx.x) >> 6);
  int lane = threadIdx.x & 63;
  if (gw >= n) return;
  const Tin* xr = x + (size_t)gw * D;
  float xa = ld1(&xr[lane]), xb = ld1(&xr[lane + 64]);
  float p0 = xa * u0[lane] + xb * u0[lane + 64];
  float p1 = xa * u1[lane] + xb * u1[lane + 64];
  float p2 = xa * u2[lane] + xb * u2[lane + 64];
  float p3 = xa * u3[lane] + xb * u3[lane + 64];
  #pragma unroll
  for (int off = 32; off; off >>= 1) {
    p0 += __shfl_xor(p0, off);
    p1 += __shfl_xor(p1, off);
    p2 += __shfl_xor(p2, off);
    p3 += __shfl_xor(p3, off);
  }
  if (lane == 0) { o0[gw] = p0; o1[gw] = p1; o2[gw] = p2; o3[gw] = p3; }
}

template<typename Tin>
__global__ void vec2_kernel(const Tin* __restrict__ x,
                            const float* __restrict__ u0, const float* __restrict__ u1,
                            float* __restrict__ o0, float* __restrict__ o1, int n) {
  int gw = (int)(((size_t)blockIdx.x * blockDim.x + threadIdx.x) >> 6);
  int lane = threadIdx.x & 63;
  if (gw >= n) return;
  const Tin* xr = x + (size_t)gw * D;
  float xa = ld1(&xr[lane]), xb = ld1(&xr[lane + 64]);
  float p0 = xa * u0[lane] + xb * u0[lane + 64];
  float p1 = xa * u1[lane] + xb * u1[lane + 64];
  #pragma unroll
  for (int off = 32; off; off >>= 1) {
    p0 += __shfl_xor(p0, off);
    p1 += __shfl_xor(p1, off);
  }
  if (lane == 0) { o0[gw] = p0; o1[gw] = p1; }
}

// ---------- H = X @ W via split-bf16 MFMA (fp32-equivalent accuracy) ----------
// block: 64 rows x 128 cols; 4 waves, each 16 rows x 128 cols (8 col-tiles).
// A-frag: row=lane&15, k=(lane>>4)*8+j (8 consecutive k).  B-frag from WT[col][k].
// C/D: col=lane&15, row=(lane>>4)*4+reg  ->  LDS transpose -> coalesced store.
template<typename Tin, typename Tout>
__global__ __launch_bounds__(256) void mfma_matmul_kernel(
    const Tin* __restrict__ X, const short* __restrict__ WhT, const short* __restrict__ WlT,
    Tout* __restrict__ H, int nrows) {
  __shared__ __align__(16) char lds_raw[34816];     // Xh[64][136] + Xl[64][136] bf16
  short* Xh = (short*)lds_raw;
  short* Xl = Xh + 64 * 136;
  int tid = threadIdx.x;
  int row0 = blockIdx.x * 64;

  // stage + split X (clamped rows for tail safety)
  for (int i = tid * 4; i < 64 * D; i += 1024) {
    int r = i >> 7, c = i & 127;
    int gr = row0 + r; if (gr >= nrows) gr = nrows - 1;
    const Tin* src = X + (size_t)gr * D + c;
    float2 v01 = ld2(src), v23 = ld2(src + 2);
    int o = r * 136 + c;
    short h0 = f2bf(v01.x), h1 = f2bf(v01.y), h2 = f2bf(v23.x), h3 = f2bf(v23.y);
    Xh[o] = h0; Xh[o + 1] = h1; Xh[o + 2] = h2; Xh[o + 3] = h3;
    Xl[o]     = f2bf(v01.x - bf2f(h0));
    Xl[o + 1] = f2bf(v01.y - bf2f(h1));
    Xl[o + 2] = f2bf(v23.x - bf2f(h2));
    Xl[o + 3] = f2bf(v23.y - bf2f(h3));
  }
  __syncthreads();

  int wv = tid >> 6, lane = tid & 63;
  int c15 = lane & 15, q = lane >> 4;
  const short* arowh = Xh + (wv * 16 + c15) * 136 + q * 8;
  const short* arowl = Xl + (wv * 16 + c15) * 136 + q * 8;
  const short* wbh = WhT + c15 * D + q * 8;
  const short* wbl = WlT + c15 * D + q * 8;

  f32x4 acc[8];
  #pragma unroll
  for (int t = 0; t < 8; ++t) acc[t] = (f32x4){0.f, 0.f, 0.f, 0.f};

  for (int ks = 0; ks < 4; ++ks) {
    short8v ah = *(const short8v*)(arowh + ks * 32);
    short8v al = *(const short8v*)(arowl + ks * 32);
    #pragma unroll
    for (int t = 0; t < 8; ++t) {
      short8v bh = *(const short8v*)(wbh + t * 16 * D + ks * 32);
      short8v bl = *(const short8v*)(wbl + t * 16 * D + ks * 32);
      acc[t] = mfma16(ah, bh, acc[t]);
      acc[t] = mfma16(ah, bl, acc[t]);
      acc[t] = mfma16(al, bh, acc[t]);
    }
  }

  __syncthreads();                    // all waves done with Xh/Xl
  float* Cb = (float*)lds_raw;        // [64][132] fp32 (33792 B)
  int rbase = wv * 16 + q * 4;
  #pragma unroll
  for (int t = 0; t < 8; ++t) {
    int col = t * 16 + c15;
    Cb[(rbase + 0) * 132 + col] = acc[t][0];
    Cb[(rbase + 1) * 132 + col] = acc[t][1];
    Cb[(rbase + 2) * 132 + col] = acc[t][2];
    Cb[(rbase + 3) * 132 + col] = acc[t][3];
  }
  __syncthreads();
  for (int i = tid * 2; i < 64 * D; i += 512) {
    int r = i >> 7, c = i & 127;
    int gr = row0 + r;
    if (gr < nrows) st2(&H[(size_t)gr * D + c], Cb[r * 132 + c], Cb[r * 132 + c + 1]);
  }
}

// ---------- GAT aggregation: one wave per destination node ----------
template<typename T>
__global__ void agg_kernel(const int* __restrict__ rowptr, const int* __restrict__ col,
                           const float* __restrict__ es, const float* __restrict__ ed,
                           const T* __restrict__ hs, const float* __restrict__ bias,
                           T* __restrict__ out, int ndst, int mode) {
  int gw = (int)(((size_t)blockIdx.x * blockDim.x + threadIdx.x) >> 6);
  int lane = threadIdx.x & 63;
  if (gw >= ndst) return;
  int p0 = rowptr[gw];
  int deg = rowptr[gw + 1] - p0;
  float a0 = 0.f, a1 = 0.f;
  if (deg > 0) {
    float edst = ed[gw];
    if (deg <= 64) {
      int s = 0; float e = -3.0e38f;
      if (lane < deg) {
        s = col[p0 + lane];
        float t = es[s] + edst;
        e = t > 0.f ? t : 0.2f * t;
      }
      float m = e;
      #pragma unroll
      for (int off = 32; off; off >>= 1) m = fmaxf(m, __shfl_xor(m, off));
      float ex = (lane < deg) ? __expf(e - m) : 0.f;
      float den = ex;
      #pragma unroll
      for (int off = 32; off; off >>= 1) den += __shfl_xor(den, off);
      float al = ex / (den + 1e-16f);
      for (int q = 0; q < deg; ++q) {
        float alpha = __shfl(al, q);
        int sq = __shfl(s, q);
        float2 h = ld2(&hs[(size_t)sq * D + 2 * lane]);
        a0 += alpha * h.x;
        a1 += alpha * h.y;
      }
    } else {
      float m = -3.0e38f;
      for (int j = lane; j < deg; j += 64) {
        int s = col[p0 + j];
        float t = es[s] + edst;
        t = t > 0.f ? t : 0.2f * t;
        m = fmaxf(m, t);
      }
      #pragma unroll
      for (int off = 32; off; off >>= 1) m = fmaxf(m, __shfl_xor(m, off));
      float den = 0.f;
      for (int j = lane; j < deg; j += 64) {
        int s = col[p0 + j];
        float t = es[s] + edst;
        t = t > 0.f ? t : 0.2f * t;
        den += __expf(t - m);
      }
      #pragma unroll
      for (int off = 32; off; off >>= 1) den += __shfl_xor(den, off);
      float inv = 1.f / (den + 1e-16f);
      for (int c = 0; c < deg; c += 64) {
        int j = c + lane;
        int s = 0; float al = 0.f;
        if (j < deg) {
          s = col[p0 + j];
          float t = es[s] + edst;
          t = t > 0.f ? t : 0.2f * t;
          al = __expf(t - m) * inv;
        }
        int cnt = deg - c; if (cnt > 64) cnt = 64;
        for (int q = 0; q < cnt; ++q) {
          float alpha = __shfl(al, q);
          int sq = __shfl(s, q);
          float2 h = ld2(&hs[(size_t)sq * D + 2 * lane]);
          a0 += alpha * h.x;
          a1 += alpha * h.y;
        }
      }
    }
  }
  float b0 = bias[2 * lane], b1 = bias[2 * lane + 1];
  size_t o = (size_t)gw * D + 2 * lane;
  if (mode == 0) {
    st2(&out[o], a0 + b0, a1 + b1);
  } else if (mode == 1) {
    float2 cur = ld2(&out[o]);
    float v0 = cur.x + a0 + b0, v1 = cur.y + a1 + b1;
    st2(&out[o], v0 > 0.f ? v0 : 0.f, v1 > 0.f ? v1 : 0.f);
  } else {
    float v0 = a0 + b0, v1 = a1 + b1;
    st2(&out[o], v0 > 0.f ? v0 : 0.f, v1 > 0.f ? v1 : 0.f);
  }
}

// ---------- pooling over sorted batch ids ----------
template<typename T>
__global__ void pool_kernel(const T* __restrict__ xv, const int* __restrict__ batch,
                            float* __restrict__ pooled, float* __restrict__ cntf, int rowsPerBlock) {
  int j = threadIdx.x;      // 0..127
  int r0 = blockIdx.x * rowsPerBlock;
  int cur = batch[r0];
  float s = 0.f;
  int run = 0;
  for (int r = r0; r < r0 + rowsPerBlock; ++r) {
    int b = batch[r];
    if (b != cur) {
      atomicAdd(&pooled[(size_t)cur * D + j], s);
      if (j == 0) atomicAdd(&cntf[cur], (float)run);
      s = 0.f; run = 0; cur = b;
    }
    s += ld1(&xv[(size_t)r * D + j]);
    run++;
  }
  atomicAdd(&pooled[(size_t)cur * D + j], s);
  if (j == 0) atomicAdd(&cntf[cur], (float)run);
}

// ---------- final MLP (single block) ----------
__global__ void mlp_kernel(const float* __restrict__ pooled, const float* __restrict__ cntf,
                           const float* __restrict__ w1, const float* __restrict__ b1,
                           const float* __restrict__ w2, const float* __restrict__ b2,
                           float* __restrict__ out, int B) {
  __shared__ float P[32 * D];
  __shared__ float Hs[32 * D];
  int tid = threadIdx.x;
  if (B > 32) return;
  for (int i = tid; i < B * D; i += 256) {
    int r = i >> 7;
    P[i] = pooled[i] / fmaxf(cntf[r], 1.0f);
  }
  __syncthreads();
  for (int i = tid; i < B * D; i += 256) {
    int r = i >> 7, j = i & 127;
    float s = b1[j];
    for (int k = 0; k < D; ++k) s += P[r * D + k] * w1[k * D + j];
    Hs[i] = s > 0.f ? s : 0.f;
  }
  __syncthreads();
  if (tid < B) {
    float s = b2[0];
    for (int j = 0; j < D; ++j) s += Hs[tid * D + j] * w2[j];
    out[tid] = s;
  }
}

__global__ void zero_kernel(float* __restrict__ o, int n) {
  int i = blockIdx.x * blockDim.x + threadIdx.x;
  if (i < n) o[i] = 0.f;
}

// ---------- full pipeline, templated on storage type ----------
template<typename T>
static void run_all(const float* x_var, const float* x_con,
                    const float* W_src, const float* W_dst,
                    const float* att_src, const float* att_dst, const float* bias,
                    const float* mlp_w1, const float* mlp_b1,
                    const float* mlp_w2, const float* mlp_b2,
                    const int* e_neg_src, const int* e_neg_dst,
                    const int* e_con_src, const int* e_con_dst, const int* batch_var,
                    int V, int C, int L, int EN, int EC, int B,
                    char* ws, float* out, hipStream_t stream) {
  size_t off = 0;
  auto alloc = [&](size_t bytes) -> char* {
    char* p = ws + off;
    off = (off + bytes + 255) & ~(size_t)255;
    return p;
  };
  T* xv0 = (T*)alloc((size_t)V * D * sizeof(T));
  T* xv1 = (T*)alloc((size_t)V * D * sizeof(T));
  T* xc  = (T*)alloc((size_t)C * D * sizeof(T));
  T* hs  = (T*)alloc((size_t)V * D * sizeof(T));
  float* es0 = (float*)alloc((size_t)V * 4);
  float* ed0 = (float*)alloc((size_t)V * 4);
  float* es1 = (float*)alloc((size_t)V * 4);
  float* ed2 = (float*)alloc((size_t)V * 4);
  float* es2 = (float*)alloc((size_t)C * 4);
  float* ed1 = (float*)alloc((size_t)C * 4);
  float* u   = (float*)alloc((size_t)L * 3 * 2 * D * 4);
  short* whT = (short*)alloc((size_t)L * 3 * D * D * 2);
  short* wlT = (short*)alloc((size_t)L * 3 * D * D * 2);
  int* rp0  = (int*)alloc((size_t)(V + 1) * 4);
  int* cur0 = (int*)alloc((size_t)V * 4);
  int* col0 = (int*)alloc((size_t)EN * 4);
  int* rp1  = (int*)alloc((size_t)(C + 1) * 4);
  int* cur1 = (int*)alloc((size_t)C * 4);
  int* col1 = (int*)alloc((size_t)EC * 4);
  int* rp2  = (int*)alloc((size_t)(V + 1) * 4);
  int* cur2 = (int*)alloc((size_t)V * 4);
  int* col2 = (int*)alloc((size_t)EC * 4);
  int* bsums = (int*)alloc((size_t)1024 * 4);
  float* pooled = (float*)alloc((size_t)B * D * 4);
  float* cntf   = (float*)alloc((size_t)B * 4);

  hipMemsetAsync(cur0, 0, (size_t)V * 4, stream);
  hipMemsetAsync(cur1, 0, (size_t)C * 4, stream);
  hipMemsetAsync(cur2, 0, (size_t)V * 4, stream);
  hipMemsetAsync(pooled, 0, (size_t)B * D * 4, stream);
  hipMemsetAsync(cntf, 0, (size_t)B * 4, stream);

  compute_u_kernel<<<dim3(L * 3, 2), D, 0, stream>>>(W_src, W_dst, att_src, att_dst, u);
  wsplit_kernel<<<L * 3, 256, 0, stream>>>(W_src, whT, wlT);

  const int tb = 256;
  count_kernel<<<(EN + tb - 1) / tb, tb, 0, stream>>>(e_neg_dst, cur0, EN);
  count2_kernel<<<(EC + tb - 1) / tb, tb, 0, stream>>>(e_con_src, e_con_dst, cur1, cur2, EC);

  auto scan = [&](int* cnt_and_cur, int* rowptr, int n) {
    int per_block = ((n + 1023) / 1024 + 255) & ~255;
    if (per_block < 256) per_block = 256;
    int nb = (n + per_block - 1) / per_block;
    bsum_kernel<<<nb, 256, 0, stream>>>(cnt_and_cur, bsums, n, per_block);
    bscan_kernel<<<1, 1024, 0, stream>>>(bsums, nb, rowptr + n);
    scan_fill_kernel<<<nb, 256, 0, stream>>>(cnt_and_cur, bsums, rowptr, cnt_and_cur, n, per_block);
  };
  scan(cur0, rp0, V);
  scan(cur1, rp1, C);
  scan(cur2, rp2, V);

  fill_kernel<<<(EN + tb - 1) / tb, tb, 0, stream>>>(e_neg_dst, e_neg_src, cur0, col0, EN);
  fill2_kernel<<<(EC + tb - 1) / tb, tb, 0, stream>>>(e_con_src, e_con_dst, cur1, cur2, col1, col2, EC);

  auto U  = [&](int l, int rel, int side) { return u + (((size_t)l * 3 + rel) * 2 + side) * D; };
  auto Wh = [&](int l, int rel) { return whT + ((size_t)l * 3 + rel) * D * D; };
  auto Wl = [&](int l, int rel) { return wlT + ((size_t)l * 3 + rel) * D * D; };
  auto Bp = [&](int l, int rel) { return bias + ((size_t)l * 3 + rel) * D; };

  int gV = (V + 63) / 64, gC = (C + 63) / 64;
  T* xv_final = xv0;
  for (int l = 0; l < L; ++l) {
    if (l == 0) {
      vec4_kernel<float><<<(V + 3) / 4, 256, 0, stream>>>(
          x_var, U(l,0,0), U(l,0,1), U(l,1,0), U(l,2,1), es0, ed0, es1, ed2, V);
      vec2_kernel<float><<<(C + 3) / 4, 256, 0, stream>>>(
          x_con, U(l,2,0), U(l,1,1), es2, ed1, C);
      mfma_matmul_kernel<float, T><<<gV, 256, 0, stream>>>(x_var, Wh(l,0), Wl(l,0), hs, V);
      agg_kernel<T><<<(V + 3) / 4, 256, 0, stream>>>(rp0, col0, es0, ed0, hs, Bp(l,0), xv0, V, 0);
      mfma_matmul_kernel<float, T><<<gC, 256, 0, stream>>>(x_con, Wh(l,2), Wl(l,2), hs, C);
      agg_kernel<T><<<(V + 3) / 4, 256, 0, stream>>>(rp2, col2, es2, ed2, hs, Bp(l,2), xv0, V, 1);
      mfma_matmul_kernel<float, T><<<gV, 256, 0, stream>>>(x_var, Wh(l,1), Wl(l,1), hs, V);
      agg_kernel<T><<<(C + 3) / 4, 256, 0, stream>>>(rp1, col1, es1, ed1, hs, Bp(l,1), xc, C, 2);
      xv_final = xv0;
    } else {
      T* xin  = (l & 1) ? xv0 : xv1;
      T* xout = (l & 1) ? xv1 : xv0;
      vec4_kernel<T><<<(V + 3) / 4, 256, 0, stream>>>(
          xin, U(l,0,0), U(l,0,1), U(l,1,0), U(l,2,1), es0, ed0, es1, ed2, V);
      vec2_kernel<T><<<(C + 3) / 4, 256, 0, stream>>>(
          xc, U(l,2,0), U(l,1,1), es2, ed1, C);
      mfma_matmul_kernel<T, T><<<gV, 256, 0, stream>>>(xin, Wh(l,0), Wl(l,0), hs, V);
      agg_kernel<T><<<(V + 3) / 4, 256, 0, stream>>>(rp0, col0, es0, ed0, hs, Bp(l,0), xout, V, 0);
      mfma_matmul_kernel<T, T><<<gC, 256, 0, stream>>>(xc, Wh(l,2), Wl(l,2), hs, C);
      agg_kernel<T><<<(V + 3) / 4, 256, 0, stream>>>(rp2, col2, es2, ed2, hs, Bp(l,2), xout, V, 1);
      mfma_matmul_kernel<T, T><<<gV, 256, 0, stream>>>(xin, Wh(l,1), Wl(l,1), hs, V);
      agg_kernel<T><<<(C + 3) / 4, 256, 0, stream>>>(rp1, col1, es1, ed1, hs, Bp(l,1), xc, C, 2);
      xv_final = xout;
    }
  }

  pool_kernel<T><<<V / 128, 128, 0, stream>>>(xv_final, batch_var, pooled, cntf, 128);
  mlp_kernel<<<1, 256, 0, stream>>>(pooled, cntf, mlp_w1, mlp_b1, mlp_w2, mlp_b2, out, B);
}

extern "C" void kernel_launch(void* const* d_in, const int* in_sizes, int n_in,
                              void* d_out, int out_size, void* d_ws, size_t ws_size,
                              hipStream_t stream) {
  const float* x_var   = (const float*)d_in[0];
  const float* x_con   = (const float*)d_in[1];
  const float* W_src   = (const float*)d_in[2];
  const float* W_dst   = (const float*)d_in[3];
  const float* att_src = (const float*)d_in[4];
  const float* att_dst = (const float*)d_in[5];
  const float* bias    = (const float*)d_in[6];
  const float* mlp_w1  = (const float*)d_in[7];
  const float* mlp_b1  = (const float*)d_in[8];
  const float* mlp_w2  = (const float*)d_in[9];
  const float* mlp_b2  = (const float*)d_in[10];
  const int* e_neg_src = (const int*)d_in[11];
  const int* e_neg_dst = (const int*)d_in[12];
  const int* e_con_src = (const int*)d_in[13];
  const int* e_con_dst = (const int*)d_in[14];
  const int* batch_var = (const int*)d_in[15];
  (void)n_in;

  const int V  = in_sizes[0] / D;
  const int C  = in_sizes[1] / D;
  const int L  = in_sizes[2] / (3 * D * D);
  const int EN = in_sizes[11];
  const int EC = in_sizes[13];
  const int B  = out_size;

  auto plan = [&](size_t esz) -> size_t {
    size_t o = 0;
    auto add = [&](size_t b) { o = (o + b + 255) & ~(size_t)255; };
    add((size_t)V * D * esz); add((size_t)V * D * esz);
    add((size_t)C * D * esz); add((size_t)V * D * esz);
    add((size_t)V * 4); add((size_t)V * 4); add((size_t)V * 4); add((size_t)V * 4);
    add((size_t)C * 4); add((size_t)C * 4);
    add((size_t)L * 3 * 2 * D * 4);
    add((size_t)L * 3 * D * D * 2); add((size_t)L * 3 * D * D * 2);
    add((size_t)(V + 1) * 4); add((size_t)V * 4); add((size_t)EN * 4);
    add((size_t)(C + 1) * 4); add((size_t)C * 4); add((size_t)EC * 4);
    add((size_t)(V + 1) * 4); add((size_t)V * 4); add((size_t)EC * 4);
    add((size_t)1024 * 4);
    add((size_t)B * D * 4); add((size_t)B * 4);
    return o;
  };

  if (plan(4) <= ws_size) {
    run_all<float>(x_var, x_con, W_src, W_dst, att_src, att_dst, bias,
                   mlp_w1, mlp_b1, mlp_w2, mlp_b2,
                   e_neg_src, e_neg_dst, e_con_src, e_con_dst, batch_var,
                   V, C, L, EN, EC, B, (char*)d_ws, (float*)d_out, stream);
  } else if (plan(2) <= ws_size) {
    run_all<bf16>(x_var, x_con, W_src, W_dst, att_src, att_dst, bias,
                  mlp_w1, mlp_b1, mlp_w2, mlp_b2,
                  e_neg_src, e_neg_dst, e_con_src, e_con_dst, batch_var,
                  V, C, L, EN, EC, B, (char*)d_ws, (float*)d_out, stream);
  } else {
    zero_kernel<<<(out_size + 63) / 64, 64, 0, stream>>>((float*)d_out, out_size);
  }
}

// Round 5
// 1382.423 us; speedup vs baseline: 1.6477x; 1.0907x over previous
//
#include <hip/hip_runtime.h>
#include <hip/hip_bf16.h>
#include <cstdint>
#include <cstddef>

#define D 128

typedef __hip_bfloat16 bf16;

typedef __attribute__((ext_vector_type(8))) short short8v;   // 8 bf16 (4 VGPR)
typedef __attribute__((ext_vector_type(4))) float f32x4;     // MFMA 16x16 acc

// ---------- typed load/store helpers (storage T, compute fp32) ----------
__device__ inline float ld1(const float* p) { return *p; }
__device__ inline float ld1(const bf16* p) { return __bfloat162float(*p); }
__device__ inline float2 ld2(const float* p) { return *(const float2*)p; }
__device__ inline float2 ld2(const bf16* p) {
  __hip_bfloat162 v = *(const __hip_bfloat162*)p;
  float2 r; r.x = __bfloat162float(v.x); r.y = __bfloat162float(v.y); return r;
}
__device__ inline void st2(float* p, float a, float b) {
  float2 v; v.x = a; v.y = b; *(float2*)p = v;
}
__device__ inline void st2(bf16* p, float a, float b) {
  __hip_bfloat162 v; v.x = __float2bfloat16(a); v.y = __float2bfloat16(b);
  *(__hip_bfloat162*)p = v;
}

// bf16 bit helpers (RNE)
__device__ inline short f2bf(float x) {
  uint32_t u = __builtin_bit_cast(uint32_t, x);
  uint32_t r = (u + 0x7FFFu + ((u >> 16) & 1u)) >> 16;
  return (short)(uint16_t)r;
}
__device__ inline float bf2f(short s) {
  uint32_t u = ((uint32_t)(uint16_t)s) << 16;
  return __builtin_bit_cast(float, u);
}

__device__ inline f32x4 mfma16(short8v a, short8v b, f32x4 c) {
  return __builtin_amdgcn_mfma_f32_16x16x32_bf16(a, b, c, 0, 0, 0);
}

// ---------- u[l,rel,side][k] = sum_j W[l,rel,k,j] * a[l,rel,j] ----------
__global__ void compute_u_kernel(const float* __restrict__ Wsrc, const float* __restrict__ Wdst,
                                 const float* __restrict__ asrc, const float* __restrict__ adst,
                                 float* __restrict__ u) {
  int lr = blockIdx.x;       // (l*3+rel)
  int side = blockIdx.y;     // 0=src, 1=dst
  int k = threadIdx.x;       // 0..127
  const float* W = (side == 0 ? Wsrc : Wdst) + ((size_t)lr * D + k) * D;
  const float* a = (side == 0 ? asrc : adst) + (size_t)lr * D;
  float s = 0.f;
  for (int j = 0; j < D; ++j) s += W[j] * a[j];
  u[((size_t)lr * 2 + side) * D + k] = s;
}

// ---------- W split: Wh/Wl bf16, transposed [col][k] for contiguous B-frags ----------
__global__ void wsplit_kernel(const float* __restrict__ Wsrc,
                              short* __restrict__ WhT, short* __restrict__ WlT) {
  int lr = blockIdx.x;
  const float* W = Wsrc + (size_t)lr * D * D;
  short* wh = WhT + (size_t)lr * D * D;
  short* wl = WlT + (size_t)lr * D * D;
  for (int i = threadIdx.x; i < D * D; i += blockDim.x) {
    int k = i >> 7, c = i & 127;
    float w = W[i];                       // W[k][c]
    short h = f2bf(w);
    short l = f2bf(w - bf2f(h));
    wh[c * D + k] = h;                    // transposed
    wl[c * D + k] = l;
  }
}

// ---------- CSR build ----------
__global__ void count_kernel(const int* __restrict__ dst, int* __restrict__ cnt, int E) {
  int i = blockIdx.x * blockDim.x + threadIdx.x;
  if (i < E) atomicAdd(&cnt[dst[i]], 1);
}

__global__ void count2_kernel(const int* __restrict__ csrc, const int* __restrict__ cdst,
                              int* __restrict__ cnt_bycon, int* __restrict__ cnt_byvar, int E) {
  int i = blockIdx.x * blockDim.x + threadIdx.x;
  if (i < E) {
    atomicAdd(&cnt_bycon[cdst[i]], 1);
    atomicAdd(&cnt_byvar[csrc[i]], 1);
  }
}

// batched 3-relation scan: pass 1 (per-block sums); bsums pre-zeroed, [3][1024]
__global__ void bsum3_kernel(const int* __restrict__ c0, const int* __restrict__ c1,
                             const int* __restrict__ c2, int* __restrict__ bsums,
                             int n0, int n1, int n2, int pb0, int pb1, int pb2) {
  __shared__ int red[256];
  int y = blockIdx.y;
  const int* cnt = (y == 0) ? c0 : (y == 1) ? c1 : c2;
  int n  = (y == 0) ? n0 : (y == 1) ? n1 : n2;
  int pb = (y == 0) ? pb0 : (y == 1) ? pb1 : pb2;
  int b = blockIdx.x, t = threadIdx.x;
  int base = b * pb;
  if (base >= n) return;
  int end = base + pb; if (end > n) end = n;
  int s = 0;
  for (int i = base + t; i < end; i += 256) s += cnt[i];
  red[t] = s;
  __syncthreads();
  #pragma unroll
  for (int off = 128; off; off >>= 1) {
    if (t < off) red[t] += red[t + off];
    __syncthreads();
  }
  if (t == 0) bsums[y * 1024 + b] = red[0];
}

// pass 2: 3 blocks, each scans its 1024-entry bsums row in-place to exclusive; writes total
__global__ void bscan3_kernel(int* __restrict__ bsums,
                              int* __restrict__ t0, int* __restrict__ t1, int* __restrict__ t2) {
  __shared__ int sh[1024];
  int y = blockIdx.x, t = threadIdx.x;
  int* bs = bsums + y * 1024;
  int v = bs[t];
  sh[t] = v;
  __syncthreads();
  for (int off = 1; off < 1024; off <<= 1) {
    int u = (t >= off) ? sh[t - off] : 0;
    __syncthreads();
    sh[t] += u;
    __syncthreads();
  }
  bs[t] = sh[t] - v;
  if (t == 1023) {
    int* tot = (y == 0) ? t0 : (y == 1) ? t1 : t2;
    *tot = sh[1023];
  }
}

// pass 3: per-block scan chunk, add offset, write rowptr+cursor
__global__ void scanfill3_kernel(const int* __restrict__ c0, const int* __restrict__ c1,
                                 const int* __restrict__ c2, const int* __restrict__ bsums,
                                 int* __restrict__ rp0, int* __restrict__ rp1, int* __restrict__ rp2,
                                 int* __restrict__ cu0, int* __restrict__ cu1, int* __restrict__ cu2,
                                 int n0, int n1, int n2, int pb0, int pb1, int pb2) {
  __shared__ int sh[256];
  int y = blockIdx.y;
  const int* cnt = (y == 0) ? c0 : (y == 1) ? c1 : c2;
  int* rowptr    = (y == 0) ? rp0 : (y == 1) ? rp1 : rp2;
  int* cursor    = (y == 0) ? cu0 : (y == 1) ? cu1 : cu2;
  int n  = (y == 0) ? n0 : (y == 1) ? n1 : n2;
  int pb = (y == 0) ? pb0 : (y == 1) ? pb1 : pb2;
  int b = blockIdx.x, t = threadIdx.x;
  int base = b * pb;
  if (base >= n) return;
  int end = base + pb; if (end > n) end = n;
  int run = bsums[y * 1024 + b];
  for (int tile = base; tile < end; tile += 256) {
    int i = tile + t;
    int c = (i < end) ? cnt[i] : 0;
    __syncthreads();
    sh[t] = c;
    __syncthreads();
    for (int off = 1; off < 256; off <<= 1) {
      int u = (t >= off) ? sh[t - off] : 0;
      __syncthreads();
      sh[t] += u;
      __syncthreads();
    }
    int excl = sh[t] - c;
    if (i < end) {
      rowptr[i] = run + excl;
      cursor[i] = run + excl;
    }
    run += sh[255];
  }
}

__global__ void fill_kernel(const int* __restrict__ dst, const int* __restrict__ src,
                            int* __restrict__ cursor, int* __restrict__ col, int E) {
  int i = blockIdx.x * blockDim.x + threadIdx.x;
  if (i < E) {
    int p = atomicAdd(&cursor[dst[i]], 1);
    col[p] = src[i];
  }
}

__global__ void fill2_kernel(const int* __restrict__ csrc, const int* __restrict__ cdst,
                             int* __restrict__ cur_bycon, int* __restrict__ cur_byvar,
                             int* __restrict__ col_bycon, int* __restrict__ col_byvar, int E) {
  int i = blockIdx.x * blockDim.x + threadIdx.x;
  if (i < E) {
    int s = csrc[i], d = cdst[i];
    int p = atomicAdd(&cur_bycon[d], 1);
    col_bycon[p] = s;
    int q = atomicAdd(&cur_byvar[s], 1);
    col_byvar[q] = d;
  }
}

// ---------- matvec bundles: one wave per row ----------
template<typename Tin>
__global__ void vec4_kernel(const Tin* __restrict__ x,
                            const float* __restrict__ u0, const float* __restrict__ u1,
                            const float* __restrict__ u2, const float* __restrict__ u3,
                            float* __restrict__ o0, float* __restrict__ o1,
                            float* __restrict__ o2, float* __restrict__ o3, int n) {
  int gw = (int)(((size_t)blockIdx.x * blockDim.x + threadIdx.x) >> 6);
  int lane = threadIdx.x & 63;
  if (gw >= n) return;
  const Tin* xr = x + (size_t)gw * D;
  float xa = ld1(&xr[lane]), xb = ld1(&xr[lane + 64]);
  float p0 = xa * u0[lane] + xb * u0[lane + 64];
  float p1 = xa * u1[lane] + xb * u1[lane + 64];
  float p2 = xa * u2[lane] + xb * u2[lane + 64];
  float p3 = xa * u3[lane] + xb * u3[lane + 64];
  #pragma unroll
  for (int off = 32; off; off >>= 1) {
    p0 += __shfl_xor(p0, off);
    p1 += __shfl_xor(p1, off);
    p2 += __shfl_xor(p2, off);
    p3 += __shfl_xor(p3, off);
  }
  if (lane == 0) { o0[gw] = p0; o1[gw] = p1; o2[gw] = p2; o3[gw] = p3; }
}

template<typename Tin>
__global__ void vec2_kernel(const Tin* __restrict__ x,
                            const float* __restrict__ u0, const float* __restrict__ u1,
                            float* __restrict__ o0, float* __restrict__ o1, int n) {
  int gw = (int)(((size_t)blockIdx.x * blockDim.x + threadIdx.x) >> 6);
  int lane = threadIdx.x & 63;
  if (gw >= n) return;
  const Tin* xr = x + (size_t)gw * D;
  float xa = ld1(&xr[lane]), xb = ld1(&xr[lane + 64]);
  float p0 = xa * u0[lane] + xb * u0[lane + 64];
  float p1 = xa * u1[lane] + xb * u1[lane + 64];
  #pragma unroll
  for (int off = 32; off; off >>= 1) {
    p0 += __shfl_xor(p0, off);
    p1 += __shfl_xor(p1, off);
  }
  if (lane == 0) { o0[gw] = p0; o1[gw] = p1; }
}

// ---------- H = X @ W via split-bf16 MFMA (fp32-equivalent accuracy); H in bf16 ----------
template<typename Tin>
__global__ __launch_bounds__(256) void mfma_matmul_kernel(
    const Tin* __restrict__ X, const short* __restrict__ WhT, const short* __restrict__ WlT,
    bf16* __restrict__ H, int nrows) {
  __shared__ __align__(16) char lds_raw[34816];     // Xh[64][136] + Xl[64][136] bf16
  short* Xh = (short*)lds_raw;
  short* Xl = Xh + 64 * 136;
  int tid = threadIdx.x;
  int row0 = blockIdx.x * 64;

  // stage + split X (clamped rows for tail safety)
  for (int i = tid * 4; i < 64 * D; i += 1024) {
    int r = i >> 7, c = i & 127;
    int gr = row0 + r; if (gr >= nrows) gr = nrows - 1;
    const Tin* src = X + (size_t)gr * D + c;
    float2 v01 = ld2(src), v23 = ld2(src + 2);
    int o = r * 136 + c;
    short h0 = f2bf(v01.x), h1 = f2bf(v01.y), h2 = f2bf(v23.x), h3 = f2bf(v23.y);
    Xh[o] = h0; Xh[o + 1] = h1; Xh[o + 2] = h2; Xh[o + 3] = h3;
    Xl[o]     = f2bf(v01.x - bf2f(h0));
    Xl[o + 1] = f2bf(v01.y - bf2f(h1));
    Xl[o + 2] = f2bf(v23.x - bf2f(h2));
    Xl[o + 3] = f2bf(v23.y - bf2f(h3));
  }
  __syncthreads();

  int wv = tid >> 6, lane = tid & 63;
  int c15 = lane & 15, q = lane >> 4;
  const short* arowh = Xh + (wv * 16 + c15) * 136 + q * 8;
  const short* arowl = Xl + (wv * 16 + c15) * 136 + q * 8;
  const short* wbh = WhT + c15 * D + q * 8;
  const short* wbl = WlT + c15 * D + q * 8;

  f32x4 acc[8];
  #pragma unroll
  for (int t = 0; t < 8; ++t) acc[t] = (f32x4){0.f, 0.f, 0.f, 0.f};

  for (int ks = 0; ks < 4; ++ks) {
    short8v ah = *(const short8v*)(arowh + ks * 32);
    short8v al = *(const short8v*)(arowl + ks * 32);
    #pragma unroll
    for (int t = 0; t < 8; ++t) {
      short8v bh = *(const short8v*)(wbh + t * 16 * D + ks * 32);
      short8v bl = *(const short8v*)(wbl + t * 16 * D + ks * 32);
      acc[t] = mfma16(ah, bh, acc[t]);
      acc[t] = mfma16(ah, bl, acc[t]);
      acc[t] = mfma16(al, bh, acc[t]);
    }
  }

  __syncthreads();                    // all waves done with Xh/Xl
  float* Cb = (float*)lds_raw;        // [64][132] fp32 (33792 B)
  int rbase = wv * 16 + q * 4;
  #pragma unroll
  for (int t = 0; t < 8; ++t) {
    int col = t * 16 + c15;
    Cb[(rbase + 0) * 132 + col] = acc[t][0];
    Cb[(rbase + 1) * 132 + col] = acc[t][1];
    Cb[(rbase + 2) * 132 + col] = acc[t][2];
    Cb[(rbase + 3) * 132 + col] = acc[t][3];
  }
  __syncthreads();
  for (int i = tid * 2; i < 64 * D; i += 512) {
    int r = i >> 7, c = i & 127;
    int gr = row0 + r;
    if (gr < nrows) st2(&H[(size_t)gr * D + c], Cb[r * 132 + c], Cb[r * 132 + c + 1]);
  }
}

// ---------- per-CSR-row GAT softmax + gather (hs in bf16, 4 B/lane rows) ----------
__device__ inline void gat_row(const int* __restrict__ col, int p0, int deg,
                               const float* __restrict__ es, float edst,
                               const bf16* __restrict__ hs, int lane,
                               float& a0, float& a1) {
  if (deg <= 0) return;
  if (deg <= 64) {
    int s = 0; float e = -3.0e38f;
    if (lane < deg) {
      s = col[p0 + lane];
      float t = es[s] + edst;
      e = t > 0.f ? t : 0.2f * t;
    }
    float m = e;
    #pragma unroll
    for (int off = 32; off; off >>= 1) m = fmaxf(m, __shfl_xor(m, off));
    float ex = (lane < deg) ? __expf(e - m) : 0.f;
    float den = ex;
    #pragma unroll
    for (int off = 32; off; off >>= 1) den += __shfl_xor(den, off);
    float al = ex / (den + 1e-16f);
    for (int q = 0; q < deg; ++q) {
      float alpha = __shfl(al, q);
      int sq = __shfl(s, q);
      float2 h = ld2(&hs[(size_t)sq * D + 2 * lane]);
      a0 += alpha * h.x;
      a1 += alpha * h.y;
    }
  } else {
    float m = -3.0e38f;
    for (int j = lane; j < deg; j += 64) {
      int s = col[p0 + j];
      float t = es[s] + edst;
      t = t > 0.f ? t : 0.2f * t;
      m = fmaxf(m, t);
    }
    #pragma unroll
    for (int off = 32; off; off >>= 1) m = fmaxf(m, __shfl_xor(m, off));
    float den = 0.f;
    for (int j = lane; j < deg; j += 64) {
      int s = col[p0 + j];
      float t = es[s] + edst;
      t = t > 0.f ? t : 0.2f * t;
      den += __expf(t - m);
    }
    #pragma unroll
    for (int off = 32; off; off >>= 1) den += __shfl_xor(den, off);
    float inv = 1.f / (den + 1e-16f);
    for (int c = 0; c < deg; c += 64) {
      int j = c + lane;
      int s = 0; float al = 0.f;
      if (j < deg) {
        s = col[p0 + j];
        float t = es[s] + edst;
        t = t > 0.f ? t : 0.2f * t;
        al = __expf(t - m) * inv;
      }
      int cnt = deg - c; if (cnt > 64) cnt = 64;
      for (int q = 0; q < cnt; ++q) {
        float alpha = __shfl(al, q);
        int sq = __shfl(s, q);
        float2 h = ld2(&hs[(size_t)sq * D + 2 * lane]);
        a0 += alpha * h.x;
        a1 += alpha * h.y;
      }
    }
  }
}

// single relation: out = relu(agg + b)
template<typename T>
__global__ void agg1_kernel(const int* __restrict__ rowptr, const int* __restrict__ col,
                            const float* __restrict__ es, const float* __restrict__ ed,
                            const bf16* __restrict__ hs, const float* __restrict__ bias,
                            T* __restrict__ out, int ndst) {
  int gw = (int)(((size_t)blockIdx.x * blockDim.x + threadIdx.x) >> 6);
  int lane = threadIdx.x & 63;
  if (gw >= ndst) return;
  int p0 = rowptr[gw];
  int deg = rowptr[gw + 1] - p0;
  float a0 = 0.f, a1 = 0.f;
  gat_row(col, p0, deg, es, ed[gw], hs, lane, a0, a1);
  float v0 = a0 + bias[2 * lane], v1 = a1 + bias[2 * lane + 1];
  st2(&out[(size_t)gw * D + 2 * lane], v0 > 0.f ? v0 : 0.f, v1 > 0.f ? v1 : 0.f);
}

// fused two relations with same dst set: out = relu(aggA + aggB + bA + bB)
template<typename T>
__global__ void agg2_kernel(const int* __restrict__ rpA, const int* __restrict__ colA,
                            const float* __restrict__ esA, const float* __restrict__ edA,
                            const bf16* __restrict__ hsA, const float* __restrict__ biasA,
                            const int* __restrict__ rpB, const int* __restrict__ colB,
                            const float* __restrict__ esB, const float* __restrict__ edB,
                            const bf16* __restrict__ hsB, const float* __restrict__ biasB,
                            T* __restrict__ out, int ndst) {
  int gw = (int)(((size_t)blockIdx.x * blockDim.x + threadIdx.x) >> 6);
  int lane = threadIdx.x & 63;
  if (gw >= ndst) return;
  float a0 = 0.f, a1 = 0.f;
  int pA = rpA[gw];
  gat_row(colA, pA, rpA[gw + 1] - pA, esA, edA[gw], hsA, lane, a0, a1);
  int pB = rpB[gw];
  gat_row(colB, pB, rpB[gw + 1] - pB, esB, edB[gw], hsB, lane, a0, a1);
  float v0 = a0 + biasA[2 * lane] + biasB[2 * lane];
  float v1 = a1 + biasA[2 * lane + 1] + biasB[2 * lane + 1];
  st2(&out[(size_t)gw * D + 2 * lane], v0 > 0.f ? v0 : 0.f, v1 > 0.f ? v1 : 0.f);
}

// ---------- pooling over sorted batch ids ----------
template<typename T>
__global__ void pool_kernel(const T* __restrict__ xv, const int* __restrict__ batch,
                            float* __restrict__ pooled, float* __restrict__ cntf, int rowsPerBlock) {
  int j = threadIdx.x;      // 0..127
  int r0 = blockIdx.x * rowsPerBlock;
  int cur = batch[r0];
  float s = 0.f;
  int run = 0;
  for (int r = r0; r < r0 + rowsPerBlock; ++r) {
    int b = batch[r];
    if (b != cur) {
      atomicAdd(&pooled[(size_t)cur * D + j], s);
      if (j == 0) atomicAdd(&cntf[cur], (float)run);
      s = 0.f; run = 0; cur = b;
    }
    s += ld1(&xv[(size_t)r * D + j]);
    run++;
  }
  atomicAdd(&pooled[(size_t)cur * D + j], s);
  if (j == 0) atomicAdd(&cntf[cur], (float)run);
}

// ---------- final MLP (single block) ----------
__global__ void mlp_kernel(const float* __restrict__ pooled, const float* __restrict__ cntf,
                           const float* __restrict__ w1, const float* __restrict__ b1,
                           const float* __restrict__ w2, const float* __restrict__ b2,
                           float* __restrict__ out, int B) {
  __shared__ float P[32 * D];
  __shared__ float Hs[32 * D];
  int tid = threadIdx.x;
  if (B > 32) return;
  for (int i = tid; i < B * D; i += 256) {
    int r = i >> 7;
    P[i] = pooled[i] / fmaxf(cntf[r], 1.0f);
  }
  __syncthreads();
  for (int i = tid; i < B * D; i += 256) {
    int r = i >> 7, j = i & 127;
    float s = b1[j];
    for (int k = 0; k < D; ++k) s += P[r * D + k] * w1[k * D + j];
    Hs[i] = s > 0.f ? s : 0.f;
  }
  __syncthreads();
  if (tid < B) {
    float s = b2[0];
    for (int j = 0; j < D; ++j) s += Hs[tid * D + j] * w2[j];
    out[tid] = s;
  }
}

__global__ void zero_kernel(float* __restrict__ o, int n) {
  int i = blockIdx.x * blockDim.x + threadIdx.x;
  if (i < n) o[i] = 0.f;
}

// ---------- full pipeline, templated on feature storage type ----------
template<typename T>
static void run_all(const float* x_var, const float* x_con,
                    const float* W_src, const float* W_dst,
                    const float* att_src, const float* att_dst, const float* bias,
                    const float* mlp_w1, const float* mlp_b1,
                    const float* mlp_w2, const float* mlp_b2,
                    const int* e_neg_src, const int* e_neg_dst,
                    const int* e_con_src, const int* e_con_dst, const int* batch_var,
                    int V, int C, int L, int EN, int EC, int B,
                    char* ws, float* out, hipStream_t stream) {
  size_t off = 0;
  auto alloc = [&](size_t bytes) -> char* {
    char* p = ws + off;
    off = (off + bytes + 255) & ~(size_t)255;
    return p;
  };
  T* xv0 = (T*)alloc((size_t)V * D * sizeof(T));
  T* xv1 = (T*)alloc((size_t)V * D * sizeof(T));
  T* xc  = (T*)alloc((size_t)C * D * sizeof(T));
  bf16* hsv = (bf16*)alloc((size_t)V * D * 2);
  bf16* hsc = (bf16*)alloc((size_t)C * D * 2);
  float* es0 = (float*)alloc((size_t)V * 4);
  float* ed0 = (float*)alloc((size_t)V * 4);
  float* es1 = (float*)alloc((size_t)V * 4);
  float* ed2 = (float*)alloc((size_t)V * 4);
  float* es2 = (float*)alloc((size_t)C * 4);
  float* ed1 = (float*)alloc((size_t)C * 4);
  float* u   = (float*)alloc((size_t)L * 3 * 2 * D * 4);
  short* whT = (short*)alloc((size_t)L * 3 * D * D * 2);
  short* wlT = (short*)alloc((size_t)L * 3 * D * D * 2);
  int* rp0  = (int*)alloc((size_t)(V + 1) * 4);
  int* cur0 = (int*)alloc((size_t)V * 4);
  int* col0 = (int*)alloc((size_t)EN * 4);
  int* rp1  = (int*)alloc((size_t)(C + 1) * 4);
  int* cur1 = (int*)alloc((size_t)C * 4);
  int* col1 = (int*)alloc((size_t)EC * 4);
  int* rp2  = (int*)alloc((size_t)(V + 1) * 4);
  int* cur2 = (int*)alloc((size_t)V * 4);
  int* col2 = (int*)alloc((size_t)EC * 4);
  int* bsums = (int*)alloc((size_t)3 * 1024 * 4);
  float* pooled = (float*)alloc((size_t)B * D * 4);
  float* cntf   = (float*)alloc((size_t)B * 4);

  hipMemsetAsync(cur0, 0, (size_t)V * 4, stream);
  hipMemsetAsync(cur1, 0, (size_t)C * 4, stream);
  hipMemsetAsync(cur2, 0, (size_t)V * 4, stream);
  hipMemsetAsync(bsums, 0, (size_t)3 * 1024 * 4, stream);
  hipMemsetAsync(pooled, 0, (size_t)B * D * 4, stream);
  hipMemsetAsync(cntf, 0, (size_t)B * 4, stream);

  compute_u_kernel<<<dim3(L * 3, 2), D, 0, stream>>>(W_src, W_dst, att_src, att_dst, u);
  wsplit_kernel<<<L * 3, 256, 0, stream>>>(W_src, whT, wlT);

  const int tb = 256;
  count_kernel<<<(EN + tb - 1) / tb, tb, 0, stream>>>(e_neg_dst, cur0, EN);
  count2_kernel<<<(EC + tb - 1) / tb, tb, 0, stream>>>(e_con_src, e_con_dst, cur1, cur2, EC);

  // batched 3-relation scan (rel0: cur0/V, rel1: cur1/C, rel2: cur2/V)
  auto pbof = [](int n) {
    int pb = ((n + 1023) / 1024 + 255) & ~255;
    return pb < 256 ? 256 : pb;
  };
  int pb0 = pbof(V), pb1 = pbof(C), pb2 = pbof(V);
  int nb0 = (V + pb0 - 1) / pb0, nb1 = (C + pb1 - 1) / pb1, nb2 = (V + pb2 - 1) / pb2;
  int nbmax = nb0 > nb1 ? nb0 : nb1; if (nb2 > nbmax) nbmax = nb2;
  bsum3_kernel<<<dim3(nbmax, 3), 256, 0, stream>>>(cur0, cur1, cur2, bsums, V, C, V, pb0, pb1, pb2);
  bscan3_kernel<<<3, 1024, 0, stream>>>(bsums, rp0 + V, rp1 + C, rp2 + V);
  scanfill3_kernel<<<dim3(nbmax, 3), 256, 0, stream>>>(cur0, cur1, cur2, bsums,
                                                       rp0, rp1, rp2, cur0, cur1, cur2,
                                                       V, C, V, pb0, pb1, pb2);

  fill_kernel<<<(EN + tb - 1) / tb, tb, 0, stream>>>(e_neg_dst, e_neg_src, cur0, col0, EN);
  fill2_kernel<<<(EC + tb - 1) / tb, tb, 0, stream>>>(e_con_src, e_con_dst, cur1, cur2, col1, col2, EC);

  auto U  = [&](int l, int rel, int side) { return u + (((size_t)l * 3 + rel) * 2 + side) * D; };
  auto Wh = [&](int l, int rel) { return whT + ((size_t)l * 3 + rel) * D * D; };
  auto Wl = [&](int l, int rel) { return wlT + ((size_t)l * 3 + rel) * D * D; };
  auto Bp = [&](int l, int rel) { return bias + ((size_t)l * 3 + rel) * D; };

  int gV = (V + 63) / 64, gC = (C + 63) / 64;
  T* xv_final = xv0;
  for (int l = 0; l < L; ++l) {
    T* xin  = (l == 0) ? xv0 : ((l & 1) ? xv0 : xv1);   // placeholder, fixed below
    T* xout;
    const void* xin_v;
    if (l == 0) { xin_v = x_var; xout = xv0; }
    else if (l & 1) { xin_v = xv0; xout = xv1; }
    else { xin_v = xv1; xout = xv0; }
    (void)xin;

    if (l == 0) {
      vec4_kernel<float><<<(V + 3) / 4, 256, 0, stream>>>(
          x_var, U(l,0,0), U(l,0,1), U(l,1,0), U(l,2,1), es0, ed0, es1, ed2, V);
      vec2_kernel<float><<<(C + 3) / 4, 256, 0, stream>>>(
          x_con, U(l,2,0), U(l,1,1), es2, ed1, C);
      mfma_matmul_kernel<float><<<gV, 256, 0, stream>>>(x_var, Wh(l,0), Wl(l,0), hsv, V);
      mfma_matmul_kernel<float><<<gC, 256, 0, stream>>>(x_con, Wh(l,2), Wl(l,2), hsc, C);
      agg2_kernel<T><<<(V + 3) / 4, 256, 0, stream>>>(
          rp0, col0, es0, ed0, hsv, Bp(l,0),
          rp2, col2, es2, ed2, hsc, Bp(l,2), xout, V);
      mfma_matmul_kernel<float><<<gV, 256, 0, stream>>>(x_var, Wh(l,1), Wl(l,1), hsv, V);
      agg1_kernel<T><<<(C + 3) / 4, 256, 0, stream>>>(rp1, col1, es1, ed1, hsv, Bp(l,1), xc, C);
    } else {
      const T* xi = (const T*)xin_v;
      vec4_kernel<T><<<(V + 3) / 4, 256, 0, stream>>>(
          xi, U(l,0,0), U(l,0,1), U(l,1,0), U(l,2,1), es0, ed0, es1, ed2, V);
      vec2_kernel<T><<<(C + 3) / 4, 256, 0, stream>>>(
          xc, U(l,2,0), U(l,1,1), es2, ed1, C);
      mfma_matmul_kernel<T><<<gV, 256, 0, stream>>>(xi, Wh(l,0), Wl(l,0), hsv, V);
      mfma_matmul_kernel<T><<<gC, 256, 0, stream>>>(xc, Wh(l,2), Wl(l,2), hsc, C);
      agg2_kernel<T><<<(V + 3) / 4, 256, 0, stream>>>(
          rp0, col0, es0, ed0, hsv, Bp(l,0),
          rp2, col2, es2, ed2, hsc, Bp(l,2), xout, V);
      mfma_matmul_kernel<T><<<gV, 256, 0, stream>>>(xi, Wh(l,1), Wl(l,1), hsv, V);
      agg1_kernel<T><<<(C + 3) / 4, 256, 0, stream>>>(rp1, col1, es1, ed1, hsv, Bp(l,1), xc, C);
    }
    xv_final = xout;
  }

  pool_kernel<T><<<V / 128, 128, 0, stream>>>(xv_final, batch_var, pooled, cntf, 128);
  mlp_kernel<<<1, 256, 0, stream>>>(pooled, cntf, mlp_w1, mlp_b1, mlp_w2, mlp_b2, out, B);
}

extern "C" void kernel_launch(void* const* d_in, const int* in_sizes, int n_in,
                              void* d_out, int out_size, void* d_ws, size_t ws_size,
                              hipStream_t stream) {
  const float* x_var   = (const float*)d_in[0];
  const float* x_con   = (const float*)d_in[1];
  const float* W_src   = (const float*)d_in[2];
  const float* W_dst   = (const float*)d_in[3];
  const float* att_src = (const float*)d_in[4];
  const float* att_dst = (const float*)d_in[5];
  const float* bias    = (const float*)d_in[6];
  const float* mlp_w1  = (const float*)d_in[7];
  const float* mlp_b1  = (const float*)d_in[8];
  const float* mlp_w2  = (const float*)d_in[9];
  const float* mlp_b2  = (const float*)d_in[10];
  const int* e_neg_src = (const int*)d_in[11];
  const int* e_neg_dst = (const int*)d_in[12];
  const int* e_con_src = (const int*)d_in[13];
  const int* e_con_dst = (const int*)d_in[14];
  const int* batch_var = (const int*)d_in[15];
  (void)n_in;

  const int V  = in_sizes[0] / D;
  const int C  = in_sizes[1] / D;
  const int L  = in_sizes[2] / (3 * D * D);
  const int EN = in_sizes[11];
  const int EC = in_sizes[13];
  const int B  = out_size;

  auto plan = [&](size_t esz) -> size_t {
    size_t o = 0;
    auto add = [&](size_t b) { o = (o + b + 255) & ~(size_t)255; };
    add((size_t)V * D * esz); add((size_t)V * D * esz); add((size_t)C * D * esz);
    add((size_t)V * D * 2); add((size_t)C * D * 2);                 // hsv, hsc (bf16)
    add((size_t)V * 4); add((size_t)V * 4); add((size_t)V * 4); add((size_t)V * 4);
    add((size_t)C * 4); add((size_t)C * 4);
    add((size_t)L * 3 * 2 * D * 4);
    add((size_t)L * 3 * D * D * 2); add((size_t)L * 3 * D * D * 2);
    add((size_t)(V + 1) * 4); add((size_t)V * 4); add((size_t)EN * 4);
    add((size_t)(C + 1) * 4); add((size_t)C * 4); add((size_t)EC * 4);
    add((size_t)(V + 1) * 4); add((size_t)V * 4); add((size_t)EC * 4);
    add((size_t)3 * 1024 * 4);
    add((size_t)B * D * 4); add((size_t)B * 4);
    return o;
  };

  if (plan(4) <= ws_size) {
    run_all<float>(x_var, x_con, W_src, W_dst, att_src, att_dst, bias,
                   mlp_w1, mlp_b1, mlp_w2, mlp_b2,
                   e_neg_src, e_neg_dst, e_con_src, e_con_dst, batch_var,
                   V, C, L, EN, EC, B, (char*)d_ws, (float*)d_out, stream);
  } else if (plan(2) <= ws_size) {
    run_all<bf16>(x_var, x_con, W_src, W_dst, att_src, att_dst, bias,
                  mlp_w1, mlp_b1, mlp_w2, mlp_b2,
                  e_neg_src, e_neg_dst, e_con_src, e_con_dst, batch_var,
                  V, C, L, EN, EC, B, (char*)d_ws, (float*)d_out, stream);
  } else {
    zero_kernel<<<(out_size + 63) / 64, 64, 0, stream>>>((float*)d_out, out_size);
  }
}